// Round 6
// baseline (409.679 us; speedup 1.0000x reference)
//
#include <hip/hip_runtime.h>

#define NEG 0.2f

typedef short s16x8 __attribute__((ext_vector_type(8)));
typedef float f32x4 __attribute__((ext_vector_type(4)));
typedef float f32x2 __attribute__((ext_vector_type(2)));
typedef int i32x4 __attribute__((ext_vector_type(4)));

__device__ __forceinline__ float lrelu(float x) { return x >= 0.f ? x : NEG * x; }
__device__ __forceinline__ float elu1(float x) { return x > 0.f ? x : __expf(x) - 1.f; }

__device__ __forceinline__ ushort bf16rn(float f) {
    unsigned u = __float_as_uint(f);
    u += 0x7fffu + ((u >> 16) & 1u);
    return (ushort)(u >> 16);
}
__device__ __forceinline__ float bf16tof(ushort h) {
    return __uint_as_float(((unsigned)h) << 16);
}

// ----------------- CSR build (dst-keyed; self-loops appended as edges i>=e) -----------------
__global__ void hist_kernel(const int* __restrict__ dst, int e, int etot, int* __restrict__ deg) {
    int i = blockIdx.x * blockDim.x + threadIdx.x;
    if (i < etot) {
        int d = (i < e) ? dst[i] : (i - e);
        atomicAdd(&deg[d], 1);
    }
}

__device__ __forceinline__ int waveIncScanI(int v, int lane) {
#pragma unroll
    for (int off = 1; off < 64; off <<= 1) {
        int u = __shfl_up(v, off);
        if (lane >= off) v += u;
    }
    return v;
}

__global__ void scan1_kernel(const int* __restrict__ deg, int n,
                             int* __restrict__ rowp, int* __restrict__ bsums) {
    int t = threadIdx.x;
    int base = blockIdx.x * 2048 + t * 8;
    int vals[8];
    int sum = 0;
#pragma unroll
    for (int i = 0; i < 8; ++i) {
        int idx = base + i;
        int v = (idx < n) ? deg[idx] : 0;
        vals[i] = sum;
        sum += v;
    }
    int lane = t & 63, w = t >> 6;
    int inc = waveIncScanI(sum, lane);
    __shared__ int wsums[4];
    if (lane == 63) wsums[w] = inc;
    __syncthreads();
    int wpre = 0;
#pragma unroll
    for (int i = 0; i < 3; ++i) wpre += (i < w) ? wsums[i] : 0;
    int exc = wpre + inc - sum;
#pragma unroll
    for (int i = 0; i < 8; ++i) {
        int idx = base + i;
        if (idx < n) rowp[idx] = exc + vals[i];
    }
    if (t == 255) bsums[blockIdx.x] = wpre + inc;
}

// scan3: adds per-block prefix (computed locally from bsums — merges old scan2) and copies cursor
__global__ void scan3_kernel(int* __restrict__ rowp, const int* __restrict__ bsums,
                             int n, int total, int* __restrict__ cursor) {
    int g = blockIdx.x;
    __shared__ int spre;
    if (threadIdx.x < 64) {
        int lane = threadIdx.x;
        int v = 0;
        for (int base = lane; base < g; base += 64) v += bsums[base];
#pragma unroll
        for (int off = 32; off > 0; off >>= 1) v += __shfl_xor(v, off);
        if (lane == 0) spre = v;
    }
    __syncthreads();
    int pre = spre;
    int base = g * 2048 + threadIdx.x * 8;
#pragma unroll
    for (int i = 0; i < 8; ++i) {
        int idx = base + i;
        if (idx < n) {
            int v = rowp[idx] + pre;
            rowp[idx] = v;
            cursor[idx] = v;
        } else if (idx == n) {
            rowp[n] = total;
        }
    }
}

__global__ void fill_kernel(const int* __restrict__ src, const int* __restrict__ dst, int e,
                            int etot, int* __restrict__ cursor, int* __restrict__ col,
                            int* __restrict__ csrdst) {
    int i = blockIdx.x * blockDim.x + threadIdx.x;
    if (i < etot) {
        int s, d;
        if (i < e) { s = src[i]; d = dst[i]; }
        else { s = d = i - e; }
        int pos = atomicAdd(&cursor[d], 1);
        col[pos] = s;
        csrdst[pos] = d;
    }
}

// ----------------- W pre-pack: fp32 [128][128] -> bf16 hi/lo in MFMA B-frag order
__global__ void wpack_kernel(const float* __restrict__ w0, const float* __restrict__ w1,
                             const float* __restrict__ w2, const float* __restrict__ w3,
                             ushort* __restrict__ whi, ushort* __restrict__ wlo) {
    int idx = blockIdx.x * 256 + threadIdx.x; // 4*16384
    int layer = idx >> 14, e = idx & 16383;
    const float* W = layer == 0 ? w0 : layer == 1 ? w1 : layer == 2 ? w2 : w3;
    int k = e >> 7, c = e & 127;
    float w = W[e];
    ushort hi = bf16rn(w);
    ushort lo = bf16rn(w - bf16tof(hi));
    int kt = k >> 5, kk = k & 31, j = kk & 7;
    int ln = ((kk >> 3) << 4) | (c & 15);
    int ntg = c >> 4;
    int pos = (layer << 14) + (((kt << 3) + ntg) * 64 + ln) * 8 + j;
    whi[pos] = hi;
    wlo[pos] = lo;
}

// ----------------- MFMA split-bf16 GEMM: out[n,128] = A[n,128] @ W[128,128]
template <bool BIAS, bool AL, bool BF16OUT>
__global__ __launch_bounds__(512, 4) void gemm_mfma_kernel(
    const float* __restrict__ A, const ushort* __restrict__ whi, const ushort* __restrict__ wlo,
    const float* __restrict__ bias, void* __restrict__ outv, int n, int ntiles,
    const float* __restrict__ asrc, const float* __restrict__ adst,
    float* __restrict__ als, float* __restrict__ ald) {
    __shared__ s16x8 ahi[2][4][64];
    __shared__ s16x8 alo[2][4][64];
    int t = threadIdx.x;
    int wid = t >> 6, lane = t & 63;
    int ntp = wid & 3;    // head / 32-col pair
    int mhalf = wid >> 2; // which 16-row half

    const s16x8* wph = (const s16x8*)whi;
    const s16x8* wpl = (const s16x8*)wlo;
    s16x8 wh[4][2], wl[4][2];
#pragma unroll
    for (int kt = 0; kt < 4; ++kt)
#pragma unroll
        for (int j = 0; j < 2; ++j) {
            int ntg = ntp * 2 + j;
            wh[kt][j] = wph[((kt << 3) + ntg) * 64 + lane];
            wl[kt][j] = wpl[((kt << 3) + ntg) * 64 + lane];
        }

    int c0 = ntp * 32 + (lane & 15);
    int c1 = c0 + 16;
    float bv0 = 0.f, bv1 = 0.f;
    if (BIAS) { bv0 = bias[c0]; bv1 = bias[c1]; }
    float as0 = 0.f, as1 = 0.f, ad0 = 0.f, ad1 = 0.f;
    if (AL) {
        as0 = asrc[ntp * 32 + (lane & 15)];
        as1 = asrc[ntp * 32 + 16 + (lane & 15)];
        ad0 = adst[ntp * 32 + (lane & 15)];
        ad1 = adst[ntp * 32 + 16 + (lane & 15)];
    }

    int srow = t >> 4, skoct = t & 15;
    int smh = srow >> 4, skt = skoct >> 2;
    int sln = ((skoct & 3) << 4) | (srow & 15);

    for (int tile = blockIdx.x; tile < ntiles; tile += gridDim.x) {
        int r0 = tile * 32;
        {
            int gr = r0 + srow;
            float4 v0 = make_float4(0.f, 0.f, 0.f, 0.f), v1 = v0;
            if (gr < n) {
                const float4* rp = (const float4*)(A + (size_t)gr * 128 + skoct * 8);
                v0 = rp[0];
                v1 = rp[1];
            }
            float f[8] = {v0.x, v0.y, v0.z, v0.w, v1.x, v1.y, v1.z, v1.w};
            s16x8 hi, lo;
#pragma unroll
            for (int j = 0; j < 8; ++j) {
                ushort h = bf16rn(f[j]);
                hi[j] = (short)h;
                lo[j] = (short)bf16rn(f[j] - bf16tof(h));
            }
            ahi[smh][skt][sln] = hi;
            alo[smh][skt][sln] = lo;
        }
        __syncthreads();

        f32x4 acc0 = {0.f, 0.f, 0.f, 0.f};
        f32x4 acc1 = {0.f, 0.f, 0.f, 0.f};
#pragma unroll
        for (int kt = 0; kt < 4; ++kt) {
            s16x8 ah = ahi[mhalf][kt][lane];
            s16x8 al = alo[mhalf][kt][lane];
            acc0 = __builtin_amdgcn_mfma_f32_16x16x32_bf16(ah, wh[kt][0], acc0, 0, 0, 0);
            acc0 = __builtin_amdgcn_mfma_f32_16x16x32_bf16(ah, wl[kt][0], acc0, 0, 0, 0);
            acc0 = __builtin_amdgcn_mfma_f32_16x16x32_bf16(al, wh[kt][0], acc0, 0, 0, 0);
            acc1 = __builtin_amdgcn_mfma_f32_16x16x32_bf16(ah, wh[kt][1], acc1, 0, 0, 0);
            acc1 = __builtin_amdgcn_mfma_f32_16x16x32_bf16(ah, wl[kt][1], acc1, 0, 0, 0);
            acc1 = __builtin_amdgcn_mfma_f32_16x16x32_bf16(al, wh[kt][1], acc1, 0, 0, 0);
        }

        int rbase = r0 + mhalf * 16 + (lane >> 4) * 4;
#pragma unroll
        for (int i = 0; i < 4; ++i) {
            int r = rbase + i;
            if (r < n) {
                if (BF16OUT) {
                    ushort* outb = (ushort*)outv;
                    outb[(size_t)r * 128 + c0] = bf16rn(acc0[i] + bv0);
                    outb[(size_t)r * 128 + c1] = bf16rn(acc1[i] + bv1);
                } else {
                    float* outf = (float*)outv;
                    outf[(size_t)r * 128 + c0] = acc0[i] + bv0;
                    outf[(size_t)r * 128 + c1] = acc1[i] + bv1;
                }
            }
        }
        if (AL) {
#pragma unroll
            for (int i = 0; i < 4; ++i) {
                float ps = acc0[i] * as0 + acc1[i] * as1;
                float pd = acc0[i] * ad0 + acc1[i] * ad1;
                ps += __shfl_xor(ps, 1); ps += __shfl_xor(ps, 2);
                ps += __shfl_xor(ps, 4); ps += __shfl_xor(ps, 8);
                pd += __shfl_xor(pd, 1); pd += __shfl_xor(pd, 2);
                pd += __shfl_xor(pd, 4); pd += __shfl_xor(pd, 8);
                int r = rbase + i;
                if ((lane & 15) == 0 && r < n) {
                    als[r * 4 + ntp] = ps;
                    ald[r * 4 + ntp] = pd;
                }
            }
        }
        __syncthreads();
    }
}

// ----------------- per-edge attention weights (CSR order, incl self edges) -----------------
__global__ void ew_kernel(const int* __restrict__ col, const int* __restrict__ csrdst,
                          const float* __restrict__ als, const float* __restrict__ ald,
                          float* __restrict__ ew, int etot) {
    int p = blockIdx.x * blockDim.x + threadIdx.x;
    if (p >= etot) return;
    int s = col[p], d = csrdst[p];
    float4 a = *(const float4*)(als + (size_t)s * 4);
    float4 b = *(const float4*)(ald + (size_t)d * 4);
    f32x4 r;
    r.x = __expf(lrelu(a.x + b.x));
    r.y = __expf(lrelu(a.y + b.y));
    r.z = __expf(lrelu(a.z + b.z));
    r.w = __expf(lrelu(a.w + b.w));
    __builtin_nontemporal_store(r, (f32x4*)(ew + (size_t)p * 4));
}

// ----------------- GAT aggregation: one wave per dst node (grid-stride); bf16 rows;
// precomputed edge weights; self-loop is a regular CSR edge -----------------
template <bool CONCAT>
__global__ void agg_kernel(const ushort* __restrict__ hp, const int* __restrict__ rowp,
                           const int* __restrict__ col, const float* __restrict__ ew,
                           const float* __restrict__ bias, float* __restrict__ out, int n) {
    int lane = threadIdx.x & 63;
    int h = lane >> 4;  // head of this lane's 2 channels
    int c2 = lane * 2;  // channel base 0..126
    const float* ewh = ew + h;
    unsigned nclamp = (unsigned)(n - 1);
    float b0 = bias[c2], b1 = bias[c2 + 1];
    int wid0 = (blockIdx.x * blockDim.x + threadIdx.x) >> 6;
    int nwaves = (gridDim.x * blockDim.x) >> 6;
    for (int d = wid0; d < n; d += nwaves) {
        int start = rowp[d], end = rowp[d + 1];
        float a0 = 0.f, a1 = 0.f, esum = 0.f;
        for (int p0 = start; p0 < end; p0 += 8) {
            i32x4 ca = __builtin_nontemporal_load((const i32x4*)(col + p0));
            i32x4 cb = __builtin_nontemporal_load((const i32x4*)(col + p0 + 4));
            int sI[8] = {ca.x, ca.y, ca.z, ca.w, cb.x, cb.y, cb.z, cb.w};
            float ev[8];
            unsigned uv[8];
#pragma unroll
            for (int j = 0; j < 8; ++j) {
                unsigned s = (unsigned)sI[j];
                s = s > nclamp ? nclamp : s;
                ev[j] = __builtin_nontemporal_load(ewh + (size_t)(p0 + j) * 4);
                uv[j] = *(const unsigned*)(hp + (size_t)s * 128 + c2);
            }
#pragma unroll
            for (int j = 0; j < 8; ++j) {
                float e = (p0 + j < end) ? ev[j] : 0.f;
                a0 += e * bf16tof((ushort)(uv[j] & 0xffffu));
                a1 += e * bf16tof((ushort)(uv[j] >> 16));
                esum += e;
            }
        }
        float inv = 1.f / (esum + 1e-16f);
        a0 *= inv;
        a1 *= inv;
        if (CONCAT) {
            f32x2 o;
            o.x = elu1(a0 + b0);
            o.y = elu1(a1 + b1);
            __builtin_nontemporal_store(o, (f32x2*)(out + (size_t)d * 128 + c2));
        } else {
            // mean over heads: combine lanes {l, l^16, l^32, l^48}
            float m0 = a0 + __shfl_xor(a0, 16);
            m0 += __shfl_xor(m0, 32);
            float m1 = a1 + __shfl_xor(a1, 16);
            m1 += __shfl_xor(m1, 32);
            if (lane < 16) {
                f32x2 o;
                o.x = elu1(m0 * 0.25f + b0);
                o.y = elu1(m1 * 0.25f + b1);
                __builtin_nontemporal_store(o, (f32x2*)(out + (size_t)d * 32 + c2));
            }
        }
    }
}

// ----------------- fused mean-pool + final_proj + MLP head, one block per batch row ---------
__global__ void poolmlp_kernel(const float* __restrict__ h2, const int* __restrict__ batch,
                               int n, const float* __restrict__ w_fp,
                               const float* __restrict__ b_fp, const float* __restrict__ w_m1,
                               const float* __restrict__ b_m1, const float* __restrict__ w_m2,
                               const float* __restrict__ b_m2, float* __restrict__ out) {
    int b = blockIdx.x, t = threadIdx.x; // 256 threads
    __shared__ int sb[2];
    if (t == 0) {
        int lo = 0, hi = n;
        while (lo < hi) { int mid = (lo + hi) >> 1; if (batch[mid] < b) lo = mid + 1; else hi = mid; }
        sb[0] = lo;
        int lo2 = lo, hi2 = n;
        while (lo2 < hi2) { int mid = (lo2 + hi2) >> 1; if (batch[mid] < b + 1) lo2 = mid + 1; else hi2 = mid; }
        sb[1] = lo2;
    }
    __syncthreads();
    int lo = sb[0], hi = sb[1];
    int c = t & 31, g = t >> 5; // 8 groups of 32
    float acc = 0.f;
    for (int i = lo + g; i < hi; i += 8) acc += h2[(size_t)i * 32 + c];
    __shared__ float red[8][32];
    __shared__ float sp[32], so[128];
    red[g][c] = acc;
    __syncthreads();
    if (t < 32) {
        float s = 0.f;
#pragma unroll
        for (int g2 = 0; g2 < 8; ++g2) s += red[g2][t];
        float cnt = (float)(hi - lo);
        sp[t] = s / fmaxf(cnt, 1.f);
    }
    __syncthreads();
    if (t < 128) {
        float o = b_fp[t];
#pragma unroll 8
        for (int k = 0; k < 32; ++k) o += sp[k] * w_fp[k * 128 + t];
        so[t] = o;
    }
    __syncthreads();
    if (t < 64) {
        float hm = b_m1[t];
        for (int cc = 0; cc < 128; ++cc) hm += so[cc] * w_m1[cc * 64 + t];
        float v = fmaxf(hm, 0.f) * w_m2[t];
#pragma unroll
        for (int offd = 32; offd > 0; offd >>= 1) v += __shfl_down(v, offd);
        if (t == 0) out[b] = v + b_m2[0];
    }
}

extern "C" void kernel_launch(void* const* d_in, const int* in_sizes, int n_in,
                              void* d_out, int out_size, void* d_ws, size_t ws_size,
                              hipStream_t stream) {
    const float* x = (const float*)d_in[0];
    const int* ei = (const int*)d_in[1];
    const int* batch = (const int*)d_in[2];
    const float* w_in = (const float*)d_in[3];
    const float* b_in = (const float*)d_in[4];
    const float* w[3] = {(const float*)d_in[5], (const float*)d_in[9], (const float*)d_in[13]};
    const float* asrc[3] = {(const float*)d_in[6], (const float*)d_in[10], (const float*)d_in[14]};
    const float* adst[3] = {(const float*)d_in[7], (const float*)d_in[11], (const float*)d_in[15]};
    const float* bb[3] = {(const float*)d_in[8], (const float*)d_in[12], (const float*)d_in[16]};
    const float* w_fp = (const float*)d_in[17];
    const float* b_fp = (const float*)d_in[18];
    const float* w_m1 = (const float*)d_in[19];
    const float* b_m1 = (const float*)d_in[20];
    const float* w_m2 = (const float*)d_in[21];
    const float* b_m2 = (const float*)d_in[22];

    int n = in_sizes[0] / 128;
    int e = in_sizes[1] / 2;
    int B = out_size;
    int etot = e + n; // self-loops appended

    char* wsb = (char*)d_ws;
    size_t off = 0;
    auto alloc = [&](size_t bytes) -> void* {
        void* p = wsb + off;
        off += (bytes + 255) & ~(size_t)255;
        return p;
    };
    float* hA = (float*)alloc((size_t)n * 128 * 4);
    ushort* hBu = (ushort*)alloc((size_t)n * 128 * 2);
    float* als = (float*)alloc((size_t)n * 4 * 4);
    float* ald = (float*)alloc((size_t)n * 4 * 4);
    int* deg = (int*)alloc((size_t)n * 4);       // reused as cursor
    int* rowp = (int*)alloc((size_t)(n + 1) * 4);
    int* col = (int*)alloc((size_t)(etot + 8) * 4);
    int* csrdst = (int*)alloc((size_t)(etot + 8) * 4);
    float* ew = (float*)alloc((size_t)(etot + 8) * 4 * 4);
    int* bsums = (int*)alloc(4096);
    ushort* whi = (ushort*)alloc((size_t)4 * 16384 * 2);
    ushort* wlo = (ushort*)alloc((size_t)4 * 16384 * 2);

    const int* srcp = ei;
    const int* dstp = ei + e;

    // dst-CSR (incl self-loops) — graph shared by all 3 layers
    hipMemsetAsync(deg, 0, (size_t)n * 4, stream);
    hist_kernel<<<(etot + 255) / 256, 256, 0, stream>>>(dstp, e, etot, deg);
    int nb = (n + 2047) / 2048;
    scan1_kernel<<<nb, 256, 0, stream>>>(deg, n, rowp, bsums);
    scan3_kernel<<<nb, 256, 0, stream>>>(rowp, bsums, n, etot, deg);
    fill_kernel<<<(etot + 255) / 256, 256, 0, stream>>>(srcp, dstp, e, etot, deg, col, csrdst);

    // pre-pack all 4 weight matrices into bf16 hi/lo MFMA fragment order
    wpack_kernel<<<256, 256, 0, stream>>>(w_in, w[0], w[1], w[2], whi, wlo);

    int ntiles = (n + 31) / 32;
    int gblk = ntiles < 1024 ? ntiles : 1024;

    // input projection (bias, fp32 out, no attention logits)
    gemm_mfma_kernel<true, false, false><<<gblk, 512, 0, stream>>>(
        x, whi, wlo, b_in, hA, n, ntiles, nullptr, nullptr, nullptr, nullptr);

    // 3 GAT layers: mfma gemm hA->hBu (bf16, +fused al), edge weights, aggregate hBu->hA
    for (int L = 0; L < 3; ++L) {
        gemm_mfma_kernel<false, true, true><<<gblk, 512, 0, stream>>>(
            hA, whi + (size_t)(L + 1) * 16384, wlo + (size_t)(L + 1) * 16384, nullptr, hBu, n,
            ntiles, asrc[L], adst[L], als, ald);
        ew_kernel<<<(etot + 255) / 256, 256, 0, stream>>>(col, csrdst, als, ald, ew, etot);
        if (L < 2)
            agg_kernel<true><<<2048, 256, 0, stream>>>(hBu, rowp, col, ew, bb[L], hA, n);
        else
            agg_kernel<false><<<2048, 256, 0, stream>>>(hBu, rowp, col, ew, bb[L], hA, n);
    }

    // fused pooling + MLP head
    poolmlp_kernel<<<B, 256, 0, stream>>>(hA, batch, n, w_fp, b_fp, w_m1, b_m1, w_m2, b_m2,
                                          (float*)d_out);
}

// Round 7
// 366.796 us; speedup vs baseline: 1.1169x; 1.1169x over previous
//
#include <hip/hip_runtime.h>

#define NEG 0.2f
#define NB 32
#define BSH 12

typedef short s16x8 __attribute__((ext_vector_type(8)));
typedef float f32x4 __attribute__((ext_vector_type(4)));

__device__ __forceinline__ float lrelu(float x) { return x >= 0.f ? x : NEG * x; }
__device__ __forceinline__ float elu1(float x) { return x > 0.f ? x : __expf(x) - 1.f; }

__device__ __forceinline__ ushort bf16rn(float f) {
    unsigned u = __float_as_uint(f);
    u += 0x7fffu + ((u >> 16) & 1u);
    return (ushort)(u >> 16);
}
__device__ __forceinline__ float bf16tof(ushort h) {
    return __uint_as_float(((unsigned)h) << 16);
}

// ----------------- bucketed-CSR build: key = dst*NB + min(src>>BSH, NB-1) -----------------
__global__ void hist_kernel(const int* __restrict__ src, const int* __restrict__ dst, int e,
                            int* __restrict__ deg) {
    int i = blockIdx.x * blockDim.x + threadIdx.x;
    if (i < e) {
        unsigned b = (unsigned)src[i] >> BSH;
        if (b > NB - 1) b = NB - 1;
        atomicAdd(&deg[dst[i] * NB + b], 1);
    }
}

__device__ __forceinline__ int waveIncScanI(int v, int lane) {
#pragma unroll
    for (int off = 1; off < 64; off <<= 1) {
        int u = __shfl_up(v, off);
        if (lane >= off) v += u;
    }
    return v;
}

__global__ void scan1_kernel(const int* __restrict__ deg, int nk,
                             int* __restrict__ rowp, int* __restrict__ bsums) {
    int t = threadIdx.x;
    int base = blockIdx.x * 2048 + t * 8;
    int vals[8];
    int sum = 0;
#pragma unroll
    for (int i = 0; i < 8; ++i) {
        int idx = base + i;
        int v = (idx < nk) ? deg[idx] : 0;
        vals[i] = sum;
        sum += v;
    }
    int lane = t & 63, w = t >> 6;
    int inc = waveIncScanI(sum, lane);
    __shared__ int wsums[4];
    if (lane == 63) wsums[w] = inc;
    __syncthreads();
    int wpre = 0;
#pragma unroll
    for (int i = 0; i < 3; ++i) wpre += (i < w) ? wsums[i] : 0;
    int exc = wpre + inc - sum;
#pragma unroll
    for (int i = 0; i < 8; ++i) {
        int idx = base + i;
        if (idx < nk) rowp[idx] = exc + vals[i];
    }
    if (t == 255) bsums[blockIdx.x] = wpre + inc;
}

// scan3: per-block prefix computed locally from bsums (merged scan2), copy cursor
__global__ void scan3_kernel(int* __restrict__ rowp, const int* __restrict__ bsums,
                             int nk, int total, int* __restrict__ cursor) {
    int g = blockIdx.x;
    __shared__ int spre;
    if (threadIdx.x < 64) {
        int lane = threadIdx.x;
        int v = 0;
        for (int base = lane; base < g; base += 64) v += bsums[base];
#pragma unroll
        for (int off = 32; off > 0; off >>= 1) v += __shfl_xor(v, off);
        if (lane == 0) spre = v;
    }
    __syncthreads();
    int pre = spre;
    int base = g * 2048 + threadIdx.x * 8;
#pragma unroll
    for (int i = 0; i < 8; ++i) {
        int idx = base + i;
        if (idx < nk) {
            int v = rowp[idx] + pre;
            rowp[idx] = v;
            cursor[idx] = v;
        } else if (idx == nk) {
            rowp[nk] = total;
        }
    }
}

__global__ void fill_kernel(const int* __restrict__ src, const int* __restrict__ dst, int e,
                            int* __restrict__ cursor, int* __restrict__ col,
                            int* __restrict__ csrdst) {
    int i = blockIdx.x * blockDim.x + threadIdx.x;
    if (i < e) {
        int s = src[i], d = dst[i];
        unsigned b = (unsigned)s >> BSH;
        if (b > NB - 1) b = NB - 1;
        int pos = atomicAdd(&cursor[d * NB + b], 1);
        col[pos] = s;
        csrdst[pos] = d;
    }
}

// ----------------- W pre-pack: fp32 [128][128] -> bf16 hi/lo in MFMA B-frag order
__global__ void wpack_kernel(const float* __restrict__ w0, const float* __restrict__ w1,
                             const float* __restrict__ w2, const float* __restrict__ w3,
                             ushort* __restrict__ whi, ushort* __restrict__ wlo) {
    int idx = blockIdx.x * 256 + threadIdx.x; // 4*16384
    int layer = idx >> 14, e = idx & 16383;
    const float* W = layer == 0 ? w0 : layer == 1 ? w1 : layer == 2 ? w2 : w3;
    int k = e >> 7, c = e & 127;
    float w = W[e];
    ushort hi = bf16rn(w);
    ushort lo = bf16rn(w - bf16tof(hi));
    int kt = k >> 5, kk = k & 31, j = kk & 7;
    int ln = ((kk >> 3) << 4) | (c & 15);
    int ntg = c >> 4;
    int pos = (layer << 14) + (((kt << 3) + ntg) * 64 + ln) * 8 + j;
    whi[pos] = hi;
    wlo[pos] = lo;
}

// ----------------- MFMA split-bf16 GEMM: out[n,128](bf16) = A[n,128] @ W[128,128]
// ABF16: A rows are bf16 (exact) -> 4 MFMAs/kt; else fp32 A split hi/lo -> 6 MFMAs/kt.
template <bool BIAS, bool AL, bool ABF16>
__global__ __launch_bounds__(512, 4) void gemm_mfma_kernel(
    const void* __restrict__ Av, const ushort* __restrict__ whi, const ushort* __restrict__ wlo,
    const float* __restrict__ bias, ushort* __restrict__ outb, int n, int ntiles,
    const float* __restrict__ asrc, const float* __restrict__ adst,
    float* __restrict__ als, float* __restrict__ ald) {
    __shared__ s16x8 ahi[2][4][64];
    __shared__ s16x8 alo[2][4][64];
    int t = threadIdx.x;
    int wid = t >> 6, lane = t & 63;
    int ntp = wid & 3;    // head / 32-col pair
    int mhalf = wid >> 2; // which 16-row half

    const s16x8* wph = (const s16x8*)whi;
    const s16x8* wpl = (const s16x8*)wlo;
    s16x8 wh[4][2], wl[4][2];
#pragma unroll
    for (int kt = 0; kt < 4; ++kt)
#pragma unroll
        for (int j = 0; j < 2; ++j) {
            int ntg = ntp * 2 + j;
            wh[kt][j] = wph[((kt << 3) + ntg) * 64 + lane];
            wl[kt][j] = wpl[((kt << 3) + ntg) * 64 + lane];
        }

    int c0 = ntp * 32 + (lane & 15);
    int c1 = c0 + 16;
    float bv0 = 0.f, bv1 = 0.f;
    if (BIAS) { bv0 = bias[c0]; bv1 = bias[c1]; }
    float as0 = 0.f, as1 = 0.f, ad0 = 0.f, ad1 = 0.f;
    if (AL) {
        as0 = asrc[ntp * 32 + (lane & 15)];
        as1 = asrc[ntp * 32 + 16 + (lane & 15)];
        ad0 = adst[ntp * 32 + (lane & 15)];
        ad1 = adst[ntp * 32 + 16 + (lane & 15)];
    }

    int srow = t >> 4, skoct = t & 15;
    int smh = srow >> 4, skt = skoct >> 2;
    int sln = ((skoct & 3) << 4) | (srow & 15);

    for (int tile = blockIdx.x; tile < ntiles; tile += gridDim.x) {
        int r0 = tile * 32;
        {
            int gr = r0 + srow;
            if (ABF16) {
                const ushort* Ab = (const ushort*)Av;
                s16x8 hi = {0, 0, 0, 0, 0, 0, 0, 0};
                if (gr < n) hi = *(const s16x8*)(Ab + (size_t)gr * 128 + skoct * 8);
                ahi[smh][skt][sln] = hi;
            } else {
                const float* Af = (const float*)Av;
                float4 v0 = make_float4(0.f, 0.f, 0.f, 0.f), v1 = v0;
                if (gr < n) {
                    const float4* rp = (const float4*)(Af + (size_t)gr * 128 + skoct * 8);
                    v0 = rp[0];
                    v1 = rp[1];
                }
                float f[8] = {v0.x, v0.y, v0.z, v0.w, v1.x, v1.y, v1.z, v1.w};
                s16x8 hi, lo;
#pragma unroll
                for (int j = 0; j < 8; ++j) {
                    ushort h = bf16rn(f[j]);
                    hi[j] = (short)h;
                    lo[j] = (short)bf16rn(f[j] - bf16tof(h));
                }
                ahi[smh][skt][sln] = hi;
                alo[smh][skt][sln] = lo;
            }
        }
        __syncthreads();

        f32x4 acc0 = {0.f, 0.f, 0.f, 0.f};
        f32x4 acc1 = {0.f, 0.f, 0.f, 0.f};
#pragma unroll
        for (int kt = 0; kt < 4; ++kt) {
            s16x8 ah = ahi[mhalf][kt][lane];
            if (ABF16) {
                acc0 = __builtin_amdgcn_mfma_f32_16x16x32_bf16(ah, wh[kt][0], acc0, 0, 0, 0);
                acc0 = __builtin_amdgcn_mfma_f32_16x16x32_bf16(ah, wl[kt][0], acc0, 0, 0, 0);
                acc1 = __builtin_amdgcn_mfma_f32_16x16x32_bf16(ah, wh[kt][1], acc1, 0, 0, 0);
                acc1 = __builtin_amdgcn_mfma_f32_16x16x32_bf16(ah, wl[kt][1], acc1, 0, 0, 0);
            } else {
                s16x8 al = alo[mhalf][kt][lane];
                acc0 = __builtin_amdgcn_mfma_f32_16x16x32_bf16(ah, wh[kt][0], acc0, 0, 0, 0);
                acc0 = __builtin_amdgcn_mfma_f32_16x16x32_bf16(ah, wl[kt][0], acc0, 0, 0, 0);
                acc0 = __builtin_amdgcn_mfma_f32_16x16x32_bf16(al, wh[kt][0], acc0, 0, 0, 0);
                acc1 = __builtin_amdgcn_mfma_f32_16x16x32_bf16(ah, wh[kt][1], acc1, 0, 0, 0);
                acc1 = __builtin_amdgcn_mfma_f32_16x16x32_bf16(ah, wl[kt][1], acc1, 0, 0, 0);
                acc1 = __builtin_amdgcn_mfma_f32_16x16x32_bf16(al, wh[kt][1], acc1, 0, 0, 0);
            }
        }

        int rbase = r0 + mhalf * 16 + (lane >> 4) * 4;
#pragma unroll
        for (int i = 0; i < 4; ++i) {
            int r = rbase + i;
            if (r < n) {
                outb[(size_t)r * 128 + c0] = bf16rn(acc0[i] + bv0);
                outb[(size_t)r * 128 + c1] = bf16rn(acc1[i] + bv1);
            }
        }
        if (AL) {
#pragma unroll
            for (int i = 0; i < 4; ++i) {
                float ps = acc0[i] * as0 + acc1[i] * as1;
                float pd = acc0[i] * ad0 + acc1[i] * ad1;
                ps += __shfl_xor(ps, 1); ps += __shfl_xor(ps, 2);
                ps += __shfl_xor(ps, 4); ps += __shfl_xor(ps, 8);
                pd += __shfl_xor(pd, 1); pd += __shfl_xor(pd, 2);
                pd += __shfl_xor(pd, 4); pd += __shfl_xor(pd, 8);
                int r = rbase + i;
                if ((lane & 15) == 0 && r < n) {
                    als[r * 4 + ntp] = ps;
                    ald[r * 4 + ntp] = pd;
                }
            }
        }
        __syncthreads();
    }
}

// ----------------- per-edge attention weights (CSR order): ew[p][h] = exp(lrelu(als+ald))
__global__ void ew_kernel(const int* __restrict__ col, const int* __restrict__ csrdst,
                          const float* __restrict__ als, const float* __restrict__ ald,
                          float* __restrict__ ew, int e) {
    int p = blockIdx.x * blockDim.x + threadIdx.x;
    if (p >= e) return;
    int s = col[p], d = csrdst[p];
    float4 a = *(const float4*)(als + (size_t)s * 4);
    float4 b = *(const float4*)(ald + (size_t)d * 4);
    float4 r;
    r.x = __expf(lrelu(a.x + b.x));
    r.y = __expf(lrelu(a.y + b.y));
    r.z = __expf(lrelu(a.z + b.z));
    r.w = __expf(lrelu(a.w + b.w));
    *(float4*)(ew + (size_t)p * 4) = r;
}

// ----------------- GAT aggregation: one wave per dst node; bf16 rows; precomputed
// edge weights; src-bucket-sorted edge order; inline self-loop -----------------
template <bool CONCAT>
__global__ void agg_kernel(const ushort* __restrict__ hp, const float* __restrict__ als,
                           const float* __restrict__ ald_, const int* __restrict__ rowp,
                           const int* __restrict__ col, const float* __restrict__ ew,
                           const float* __restrict__ bias, ushort* __restrict__ outb,
                           float* __restrict__ outf, int n) {
    int wid = (blockIdx.x * blockDim.x + threadIdx.x) >> 6;
    if (wid >= n) return;
    int lane = threadIdx.x & 63;
    int d = wid;
    int h = lane >> 4;  // head of this lane's 2 channels
    int c2 = lane * 2;  // channel base 0..126
    int start = rowp[d * NB], end = rowp[d * NB + NB];
    float eself = __expf(lrelu(als[d * 4 + h] + ald_[d * 4 + h]));
    unsigned sv = *(const unsigned*)(hp + (size_t)d * 128 + c2);
    float a0 = eself * bf16tof((ushort)(sv & 0xffffu));
    float a1 = eself * bf16tof((ushort)(sv >> 16));
    float esum = eself;
    const float* ewh = ew + h;
    unsigned nclamp = (unsigned)(n - 1);
    for (int p0 = start; p0 < end; p0 += 8) {
        int4 ca = *(const int4*)(col + p0);
        int4 cb = *(const int4*)(col + p0 + 4);
        int sI[8] = {ca.x, ca.y, ca.z, ca.w, cb.x, cb.y, cb.z, cb.w};
        float ev[8];
        unsigned uv[8];
#pragma unroll
        for (int j = 0; j < 8; ++j) {
            unsigned s = (unsigned)sI[j];
            s = s > nclamp ? nclamp : s;
            ev[j] = ewh[(size_t)(p0 + j) * 4];
            uv[j] = *(const unsigned*)(hp + (size_t)s * 128 + c2);
        }
#pragma unroll
        for (int j = 0; j < 8; ++j) {
            float e = (p0 + j < end) ? ev[j] : 0.f;
            a0 += e * bf16tof((ushort)(uv[j] & 0xffffu));
            a1 += e * bf16tof((ushort)(uv[j] >> 16));
            esum += e;
        }
    }
    float inv = 1.f / (esum + 1e-16f);
    a0 *= inv;
    a1 *= inv;
    if (CONCAT) {
        float o0 = elu1(a0 + bias[c2]);
        float o1 = elu1(a1 + bias[c2 + 1]);
        unsigned pk = (unsigned)bf16rn(o0) | ((unsigned)bf16rn(o1) << 16);
        *(unsigned*)(outb + (size_t)d * 128 + c2) = pk;
    } else {
        // mean over heads: combine lanes {l, l^16, l^32, l^48}
        a0 += __shfl_xor(a0, 16); a0 += __shfl_xor(a0, 32);
        a1 += __shfl_xor(a1, 16); a1 += __shfl_xor(a1, 32);
        if (lane < 16) {
            float r0 = elu1(a0 * 0.25f + bias[c2]);
            float r1 = elu1(a1 * 0.25f + bias[c2 + 1]);
            *(float2*)(outf + (size_t)d * 32 + c2) = make_float2(r0, r1);
        }
    }
}

// ----------------- fused mean-pool + final_proj + MLP head, one block per batch row ---------
__global__ void poolmlp_kernel(const float* __restrict__ h2, const int* __restrict__ batch,
                               int n, const float* __restrict__ w_fp,
                               const float* __restrict__ b_fp, const float* __restrict__ w_m1,
                               const float* __restrict__ b_m1, const float* __restrict__ w_m2,
                               const float* __restrict__ b_m2, float* __restrict__ out) {
    int b = blockIdx.x, t = threadIdx.x; // 256 threads
    __shared__ int sb[2];
    if (t == 0) {
        int lo = 0, hi = n;
        while (lo < hi) { int mid = (lo + hi) >> 1; if (batch[mid] < b) lo = mid + 1; else hi = mid; }
        sb[0] = lo;
        int lo2 = lo, hi2 = n;
        while (lo2 < hi2) { int mid = (lo2 + hi2) >> 1; if (batch[mid] < b + 1) lo2 = mid + 1; else hi2 = mid; }
        sb[1] = lo2;
    }
    __syncthreads();
    int lo = sb[0], hi = sb[1];
    int c = t & 31, g = t >> 5; // 8 groups of 32
    float acc = 0.f;
    for (int i = lo + g; i < hi; i += 8) acc += h2[(size_t)i * 32 + c];
    __shared__ float red[8][32];
    __shared__ float sp[32], so[128];
    red[g][c] = acc;
    __syncthreads();
    if (t < 32) {
        float s = 0.f;
#pragma unroll
        for (int g2 = 0; g2 < 8; ++g2) s += red[g2][t];
        float cnt = (float)(hi - lo);
        sp[t] = s / fmaxf(cnt, 1.f);
    }
    __syncthreads();
    if (t < 128) {
        float o = b_fp[t];
#pragma unroll 8
        for (int k = 0; k < 32; ++k) o += sp[k] * w_fp[k * 128 + t];
        so[t] = o;
    }
    __syncthreads();
    if (t < 64) {
        float hm = b_m1[t];
        for (int cc = 0; cc < 128; ++cc) hm += so[cc] * w_m1[cc * 64 + t];
        float v = fmaxf(hm, 0.f) * w_m2[t];
#pragma unroll
        for (int offd = 32; offd > 0; offd >>= 1) v += __shfl_down(v, offd);
        if (t == 0) out[b] = v + b_m2[0];
    }
}

extern "C" void kernel_launch(void* const* d_in, const int* in_sizes, int n_in,
                              void* d_out, int out_size, void* d_ws, size_t ws_size,
                              hipStream_t stream) {
    const float* x = (const float*)d_in[0];
    const int* ei = (const int*)d_in[1];
    const int* batch = (const int*)d_in[2];
    const float* w_in = (const float*)d_in[3];
    const float* b_in = (const float*)d_in[4];
    const float* w[3] = {(const float*)d_in[5], (const float*)d_in[9], (const float*)d_in[13]};
    const float* asrc[3] = {(const float*)d_in[6], (const float*)d_in[10], (const float*)d_in[14]};
    const float* adst[3] = {(const float*)d_in[7], (const float*)d_in[11], (const float*)d_in[15]};
    const float* bb[3] = {(const float*)d_in[8], (const float*)d_in[12], (const float*)d_in[16]};
    const float* w_fp = (const float*)d_in[17];
    const float* b_fp = (const float*)d_in[18];
    const float* w_m1 = (const float*)d_in[19];
    const float* b_m1 = (const float*)d_in[20];
    const float* w_m2 = (const float*)d_in[21];
    const float* b_m2 = (const float*)d_in[22];

    int n = in_sizes[0] / 128;
    int e = in_sizes[1] / 2;
    int B = out_size;
    int nk = n * NB;

    char* wsb = (char*)d_ws;
    size_t off = 0;
    auto alloc = [&](size_t bytes) -> void* {
        void* p = wsb + off;
        off += (bytes + 255) & ~(size_t)255;
        return p;
    };
    ushort* hAu = (ushort*)alloc((size_t)n * 128 * 2);  // proj out / agg concat out (bf16)
    ushort* hBu = (ushort*)alloc((size_t)n * 128 * 2);  // per-layer gemm out (bf16)
    float* h3 = (float*)alloc((size_t)n * 32 * 4);      // layer-3 agg out (fp32)
    float* als = (float*)alloc((size_t)n * 4 * 4);
    float* ald = (float*)alloc((size_t)n * 4 * 4);
    int* deg = (int*)alloc((size_t)nk * 4);             // reused as cursor
    int* rowp = (int*)alloc((size_t)(nk + 1) * 4);
    int* col = (int*)alloc((size_t)(e + 8) * 4);
    int* csrdst = (int*)alloc((size_t)(e + 8) * 4);
    float* ew = (float*)alloc((size_t)(e + 8) * 4 * 4);
    int* bsums = (int*)alloc(16384);
    ushort* whi = (ushort*)alloc((size_t)4 * 16384 * 2);
    ushort* wlo = (ushort*)alloc((size_t)4 * 16384 * 2);

    const int* srcp = ei;
    const int* dstp = ei + e;

    // bucketed CSR by (dst, src-bucket) — graph shared by all 3 layers
    hipMemsetAsync(deg, 0, (size_t)nk * 4, stream);
    hist_kernel<<<(e + 255) / 256, 256, 0, stream>>>(srcp, dstp, e, deg);
    int nb = (nk + 2047) / 2048;
    scan1_kernel<<<nb, 256, 0, stream>>>(deg, nk, rowp, bsums);
    scan3_kernel<<<nb, 256, 0, stream>>>(rowp, bsums, nk, e, deg);
    fill_kernel<<<(e + 255) / 256, 256, 0, stream>>>(srcp, dstp, e, deg, col, csrdst);

    // pre-pack all 4 weight matrices into bf16 hi/lo MFMA fragment order
    wpack_kernel<<<256, 256, 0, stream>>>(w_in, w[0], w[1], w[2], whi, wlo);

    int ntiles = (n + 31) / 32;
    int gblk = ntiles < 512 ? ntiles : 512;

    // input projection (fp32 A split hi/lo, bias, bf16 out)
    gemm_mfma_kernel<true, false, false><<<gblk, 512, 0, stream>>>(
        x, whi, wlo, b_in, hAu, n, ntiles, nullptr, nullptr, nullptr, nullptr);

    // 3 GAT layers: mfma gemm hAu->hBu (bf16 A, +fused al), edge weights, aggregate
    for (int L = 0; L < 3; ++L) {
        gemm_mfma_kernel<false, true, true><<<gblk, 512, 0, stream>>>(
            hAu, whi + (size_t)(L + 1) * 16384, wlo + (size_t)(L + 1) * 16384, nullptr, hBu, n,
            ntiles, asrc[L], adst[L], als, ald);
        ew_kernel<<<(e + 255) / 256, 256, 0, stream>>>(col, csrdst, als, ald, ew, e);
        int gridAgg = (n + 3) / 4;
        if (L < 2)
            agg_kernel<true><<<gridAgg, 256, 0, stream>>>(hBu, als, ald, rowp, col, ew, bb[L],
                                                          hAu, nullptr, n);
        else
            agg_kernel<false><<<gridAgg, 256, 0, stream>>>(hBu, als, ald, rowp, col, ew, bb[L],
                                                           nullptr, h3, n);
    }

    // fused pooling + MLP head
    poolmlp_kernel<<<B, 256, 0, stream>>>(h3, batch, n, w_fp, b_fp, w_m1, b_m1, w_m2, b_m2,
                                          (float*)d_out);
}

// Round 8
// 351.796 us; speedup vs baseline: 1.1645x; 1.0426x over previous
//
#include <hip/hip_runtime.h>

#define NEG 0.2f
#define NB 32
#define BSH 12

typedef short s16x8 __attribute__((ext_vector_type(8)));
typedef float f32x4 __attribute__((ext_vector_type(4)));

__device__ __forceinline__ float lrelu(float x) { return x >= 0.f ? x : NEG * x; }
__device__ __forceinline__ float elu1(float x) { return x > 0.f ? x : __expf(x) - 1.f; }

__device__ __forceinline__ unsigned bf16rn(float f) {
    unsigned u = __float_as_uint(f);
    u += 0x7fffu + ((u >> 16) & 1u);
    return u >> 16;
}
__device__ __forceinline__ float bf16tof(ushort h) {
    return __uint_as_float(((unsigned)h) << 16);
}
__device__ __forceinline__ float bf16lo(unsigned u) { return __uint_as_float(u << 16); }
__device__ __forceinline__ float bf16hi(unsigned u) { return __uint_as_float(u & 0xffff0000u); }

// ----------------- bucketed-CSR build: key = dst*NB + min(src>>BSH, NB-1) -----------------
__global__ void hist_kernel(const int* __restrict__ src, const int* __restrict__ dst, int e,
                            int* __restrict__ deg) {
    int i = blockIdx.x * blockDim.x + threadIdx.x;
    if (i < e) {
        unsigned b = (unsigned)src[i] >> BSH;
        if (b > NB - 1) b = NB - 1;
        atomicAdd(&deg[dst[i] * NB + b], 1);
    }
}

__device__ __forceinline__ int waveIncScanI(int v, int lane) {
#pragma unroll
    for (int off = 1; off < 64; off <<= 1) {
        int u = __shfl_up(v, off);
        if (lane >= off) v += u;
    }
    return v;
}

__global__ void scan1_kernel(const int* __restrict__ deg, int nk,
                             int* __restrict__ rowp, int* __restrict__ bsums) {
    int t = threadIdx.x;
    int base = blockIdx.x * 2048 + t * 8;
    int vals[8];
    int sum = 0;
#pragma unroll
    for (int i = 0; i < 8; ++i) {
        int idx = base + i;
        int v = (idx < nk) ? deg[idx] : 0;
        vals[i] = sum;
        sum += v;
    }
    int lane = t & 63, w = t >> 6;
    int inc = waveIncScanI(sum, lane);
    __shared__ int wsums[4];
    if (lane == 63) wsums[w] = inc;
    __syncthreads();
    int wpre = 0;
#pragma unroll
    for (int i = 0; i < 3; ++i) wpre += (i < w) ? wsums[i] : 0;
    int exc = wpre + inc - sum;
#pragma unroll
    for (int i = 0; i < 8; ++i) {
        int idx = base + i;
        if (idx < nk) rowp[idx] = exc + vals[i];
    }
    if (t == 255) bsums[blockIdx.x] = wpre + inc;
}

// scan3: per-block prefix computed locally from bsums (merged scan2), copy cursor
__global__ void scan3_kernel(int* __restrict__ rowp, const int* __restrict__ bsums,
                             int nk, int total, int* __restrict__ cursor) {
    int g = blockIdx.x;
    __shared__ int spre;
    if (threadIdx.x < 64) {
        int lane = threadIdx.x;
        int v = 0;
        for (int base = lane; base < g; base += 64) v += bsums[base];
#pragma unroll
        for (int off = 32; off > 0; off >>= 1) v += __shfl_xor(v, off);
        if (lane == 0) spre = v;
    }
    __syncthreads();
    int pre = spre;
    int base = g * 2048 + threadIdx.x * 8;
#pragma unroll
    for (int i = 0; i < 8; ++i) {
        int idx = base + i;
        if (idx < nk) {
            int v = rowp[idx] + pre;
            rowp[idx] = v;
            cursor[idx] = v;
        } else if (idx == nk) {
            rowp[nk] = total;
        }
    }
}

__global__ void fill_kernel(const int* __restrict__ src, const int* __restrict__ dst, int e,
                            int* __restrict__ cursor, int* __restrict__ col) {
    int i = blockIdx.x * blockDim.x + threadIdx.x;
    if (i < e) {
        int s = src[i], d = dst[i];
        unsigned b = (unsigned)s >> BSH;
        if (b > NB - 1) b = NB - 1;
        int pos = atomicAdd(&cursor[d * NB + b], 1);
        col[pos] = s;
    }
}

// ----------------- W pre-pack: fp32 [128][128] -> bf16 hi/lo in MFMA B-frag order
__global__ void wpack_kernel(const float* __restrict__ w0, const float* __restrict__ w1,
                             const float* __restrict__ w2, const float* __restrict__ w3,
                             ushort* __restrict__ whi, ushort* __restrict__ wlo) {
    int idx = blockIdx.x * 256 + threadIdx.x; // 4*16384
    int layer = idx >> 14, e = idx & 16383;
    const float* W = layer == 0 ? w0 : layer == 1 ? w1 : layer == 2 ? w2 : w3;
    int k = e >> 7, c = e & 127;
    float w = W[e];
    ushort hi = (ushort)bf16rn(w);
    ushort lo = (ushort)bf16rn(w - bf16tof(hi));
    int kt = k >> 5, kk = k & 31, j = kk & 7;
    int ln = ((kk >> 3) << 4) | (c & 15);
    int ntg = c >> 4;
    int pos = (layer << 14) + (((kt << 3) + ntg) * 64 + ln) * 8 + j;
    whi[pos] = hi;
    wlo[pos] = lo;
}

// ----------------- MFMA split-bf16 GEMM: out[n,128](bf16) = A[n,128] @ W[128,128]
// ABF16: A rows are bf16 (exact) -> 4 MFMAs/kt; else fp32 A split hi/lo -> 6 MFMAs/kt.
template <bool BIAS, bool AL, bool ABF16>
__global__ __launch_bounds__(512, 4) void gemm_mfma_kernel(
    const void* __restrict__ Av, const ushort* __restrict__ whi, const ushort* __restrict__ wlo,
    const float* __restrict__ bias, ushort* __restrict__ outb, int n, int ntiles,
    const float* __restrict__ asrc, const float* __restrict__ adst,
    float* __restrict__ als, float* __restrict__ ald) {
    __shared__ s16x8 ahi[2][4][64];
    __shared__ s16x8 alo[2][4][64];
    int t = threadIdx.x;
    int wid = t >> 6, lane = t & 63;
    int ntp = wid & 3;    // head / 32-col pair
    int mhalf = wid >> 2; // which 16-row half

    const s16x8* wph = (const s16x8*)whi;
    const s16x8* wpl = (const s16x8*)wlo;
    s16x8 wh[4][2], wl[4][2];
#pragma unroll
    for (int kt = 0; kt < 4; ++kt)
#pragma unroll
        for (int j = 0; j < 2; ++j) {
            int ntg = ntp * 2 + j;
            wh[kt][j] = wph[((kt << 3) + ntg) * 64 + lane];
            wl[kt][j] = wpl[((kt << 3) + ntg) * 64 + lane];
        }

    int c0 = ntp * 32 + (lane & 15);
    int c1 = c0 + 16;
    float bv0 = 0.f, bv1 = 0.f;
    if (BIAS) { bv0 = bias[c0]; bv1 = bias[c1]; }
    float as0 = 0.f, as1 = 0.f, ad0 = 0.f, ad1 = 0.f;
    if (AL) {
        as0 = asrc[ntp * 32 + (lane & 15)];
        as1 = asrc[ntp * 32 + 16 + (lane & 15)];
        ad0 = adst[ntp * 32 + (lane & 15)];
        ad1 = adst[ntp * 32 + 16 + (lane & 15)];
    }

    int srow = t >> 4, skoct = t & 15;
    int smh = srow >> 4, skt = skoct >> 2;
    int sln = ((skoct & 3) << 4) | (srow & 15);

    for (int tile = blockIdx.x; tile < ntiles; tile += gridDim.x) {
        int r0 = tile * 32;
        {
            int gr = r0 + srow;
            if (ABF16) {
                const ushort* Ab = (const ushort*)Av;
                s16x8 hi = {0, 0, 0, 0, 0, 0, 0, 0};
                if (gr < n) hi = *(const s16x8*)(Ab + (size_t)gr * 128 + skoct * 8);
                ahi[smh][skt][sln] = hi;
            } else {
                const float* Af = (const float*)Av;
                float4 v0 = make_float4(0.f, 0.f, 0.f, 0.f), v1 = v0;
                if (gr < n) {
                    const float4* rp = (const float4*)(Af + (size_t)gr * 128 + skoct * 8);
                    v0 = rp[0];
                    v1 = rp[1];
                }
                float f[8] = {v0.x, v0.y, v0.z, v0.w, v1.x, v1.y, v1.z, v1.w};
                s16x8 hi, lo;
#pragma unroll
                for (int j = 0; j < 8; ++j) {
                    ushort h = (ushort)bf16rn(f[j]);
                    hi[j] = (short)h;
                    lo[j] = (short)bf16rn(f[j] - bf16tof(h));
                }
                ahi[smh][skt][sln] = hi;
                alo[smh][skt][sln] = lo;
            }
        }
        __syncthreads();

        f32x4 acc0 = {0.f, 0.f, 0.f, 0.f};
        f32x4 acc1 = {0.f, 0.f, 0.f, 0.f};
#pragma unroll
        for (int kt = 0; kt < 4; ++kt) {
            s16x8 ah = ahi[mhalf][kt][lane];
            if (ABF16) {
                acc0 = __builtin_amdgcn_mfma_f32_16x16x32_bf16(ah, wh[kt][0], acc0, 0, 0, 0);
                acc0 = __builtin_amdgcn_mfma_f32_16x16x32_bf16(ah, wl[kt][0], acc0, 0, 0, 0);
                acc1 = __builtin_amdgcn_mfma_f32_16x16x32_bf16(ah, wh[kt][1], acc1, 0, 0, 0);
                acc1 = __builtin_amdgcn_mfma_f32_16x16x32_bf16(ah, wl[kt][1], acc1, 0, 0, 0);
            } else {
                s16x8 al = alo[mhalf][kt][lane];
                acc0 = __builtin_amdgcn_mfma_f32_16x16x32_bf16(ah, wh[kt][0], acc0, 0, 0, 0);
                acc0 = __builtin_amdgcn_mfma_f32_16x16x32_bf16(ah, wl[kt][0], acc0, 0, 0, 0);
                acc0 = __builtin_amdgcn_mfma_f32_16x16x32_bf16(al, wh[kt][0], acc0, 0, 0, 0);
                acc1 = __builtin_amdgcn_mfma_f32_16x16x32_bf16(ah, wh[kt][1], acc1, 0, 0, 0);
                acc1 = __builtin_amdgcn_mfma_f32_16x16x32_bf16(ah, wl[kt][1], acc1, 0, 0, 0);
                acc1 = __builtin_amdgcn_mfma_f32_16x16x32_bf16(al, wh[kt][1], acc1, 0, 0, 0);
            }
        }

        int rbase = r0 + mhalf * 16 + (lane >> 4) * 4;
#pragma unroll
        for (int i = 0; i < 4; ++i) {
            int r = rbase + i;
            if (r < n) {
                outb[(size_t)r * 128 + c0] = (ushort)bf16rn(acc0[i] + bv0);
                outb[(size_t)r * 128 + c1] = (ushort)bf16rn(acc1[i] + bv1);
            }
        }
        if (AL) {
#pragma unroll
            for (int i = 0; i < 4; ++i) {
                float ps = acc0[i] * as0 + acc1[i] * as1;
                float pd = acc0[i] * ad0 + acc1[i] * ad1;
                ps += __shfl_xor(ps, 1); ps += __shfl_xor(ps, 2);
                ps += __shfl_xor(ps, 4); ps += __shfl_xor(ps, 8);
                pd += __shfl_xor(pd, 1); pd += __shfl_xor(pd, 2);
                pd += __shfl_xor(pd, 4); pd += __shfl_xor(pd, 8);
                int r = rbase + i;
                if ((lane & 15) == 0 && r < n) {
                    als[r * 4 + ntp] = ps;
                    ald[r * 4 + ntp] = pd;
                }
            }
        }
        __syncthreads();
    }
}

// ----------------- GAT aggregation: TWO nodes per wave (32 lanes / 4 channels each);
// exp(lrelu(..)) computed in-kernel by lane specialization (j=slot, hh=head) + shfl;
// bf16 rows; src-bucket-sorted edges; inline self-loop -----------------
template <bool CONCAT>
__global__ void agg_kernel(const ushort* __restrict__ hp, const float* __restrict__ als,
                           const float* __restrict__ ald_, const int* __restrict__ rowp,
                           const int* __restrict__ col, const float* __restrict__ bias,
                           ushort* __restrict__ outb, float* __restrict__ outf, int n) {
    int lane = threadIdx.x & 63;
    int hl = lane & 31;   // lane within half-wave
    int wid = (blockIdx.x * blockDim.x + threadIdx.x) >> 6;
    int d = wid * 2 + (lane >> 5);
    bool valid = d < n;
    int dc = valid ? d : (n - 1);

    int h = hl >> 3;      // data head (this lane's 4 channels)
    int c4 = hl * 4;      // channel base 0..124
    int hh = hl & 3;      // exp-duty head
    int jl = hl >> 2;     // exp-duty edge slot 0..7
    int bshf = lane & 32; // half base for shuffles

    int start = rowp[dc * NB];
    int end = valid ? rowp[dc * NB + NB] : start;

    float aldv_hh = ald_[dc * 4 + hh];
    float eself = __expf(lrelu(als[dc * 4 + h] + ald_[dc * 4 + h]));

    uint2 sv = *(const uint2*)(hp + (size_t)dc * 128 + c4);
    float a0 = eself * bf16lo(sv.x), a1 = eself * bf16hi(sv.x);
    float a2 = eself * bf16lo(sv.y), a3 = eself * bf16hi(sv.y);
    float esum = eself;

    int iters = (end - start + 7) >> 3;
    int oiters = __shfl_xor(iters, 32);
    int maxit = iters > oiters ? iters : oiters;
    unsigned nclamp = (unsigned)(n - 1);

    for (int it = 0; it < maxit; ++it) {
        int p0 = start + it * 8;
        bool act = p0 < end;
        int pc = act ? p0 : start;
        int4 ca = *(const int4*)(col + pc);
        int4 cb = *(const int4*)(col + pc + 4);
        // exp duty: this lane's (edge jl, head hh)
        unsigned se = (unsigned)col[pc + jl];
        se = se > nclamp ? nclamp : se;
        float ee = __expf(lrelu(als[(size_t)se * 4 + hh] + aldv_hh));
        ee = (act && (p0 + jl < end)) ? ee : 0.f;

#define EDGE(JJ, SRC)                                                              \
        {                                                                          \
            float ej = __shfl(ee, bshf | (JJ << 2) | h);                           \
            unsigned sju = (unsigned)(SRC);                                        \
            sju = sju > nclamp ? nclamp : sju;                                     \
            uint2 uv = *(const uint2*)(hp + (size_t)sju * 128 + c4);               \
            a0 += ej * bf16lo(uv.x); a1 += ej * bf16hi(uv.x);                      \
            a2 += ej * bf16lo(uv.y); a3 += ej * bf16hi(uv.y);                      \
            esum += ej;                                                            \
        }
        EDGE(0, ca.x) EDGE(1, ca.y) EDGE(2, ca.z) EDGE(3, ca.w)
        EDGE(4, cb.x) EDGE(5, cb.y) EDGE(6, cb.z) EDGE(7, cb.w)
#undef EDGE
    }

    float inv = 1.f / (esum + 1e-16f);
    a0 *= inv; a1 *= inv; a2 *= inv; a3 *= inv;
    if (CONCAT) {
        if (valid) {
            float o0 = elu1(a0 + bias[c4]);
            float o1 = elu1(a1 + bias[c4 + 1]);
            float o2 = elu1(a2 + bias[c4 + 2]);
            float o3 = elu1(a3 + bias[c4 + 3]);
            uint2 pk;
            pk.x = bf16rn(o0) | (bf16rn(o1) << 16);
            pk.y = bf16rn(o2) | (bf16rn(o3) << 16);
            *(uint2*)(outb + (size_t)d * 128 + c4) = pk;
        }
    } else {
        // mean over 4 heads: lanes {hl, hl^8, hl^16, hl^24} share channel-in-head
        a0 += __shfl_xor(a0, 8); a0 += __shfl_xor(a0, 16);
        a1 += __shfl_xor(a1, 8); a1 += __shfl_xor(a1, 16);
        a2 += __shfl_xor(a2, 8); a2 += __shfl_xor(a2, 16);
        a3 += __shfl_xor(a3, 8); a3 += __shfl_xor(a3, 16);
        if (valid && hl < 8) {
            int cin = hl * 4;
            float4 o;
            o.x = elu1(a0 * 0.25f + bias[cin]);
            o.y = elu1(a1 * 0.25f + bias[cin + 1]);
            o.z = elu1(a2 * 0.25f + bias[cin + 2]);
            o.w = elu1(a3 * 0.25f + bias[cin + 3]);
            *(float4*)(outf + (size_t)d * 32 + cin) = o;
        }
    }
}

// ----------------- fused mean-pool + final_proj + MLP head, one block per batch row ---------
__global__ void poolmlp_kernel(const float* __restrict__ h2, const int* __restrict__ batch,
                               int n, const float* __restrict__ w_fp,
                               const float* __restrict__ b_fp, const float* __restrict__ w_m1,
                               const float* __restrict__ b_m1, const float* __restrict__ w_m2,
                               const float* __restrict__ b_m2, float* __restrict__ out) {
    int b = blockIdx.x, t = threadIdx.x; // 256 threads
    __shared__ int sb[2];
    if (t == 0) {
        int lo = 0, hi = n;
        while (lo < hi) { int mid = (lo + hi) >> 1; if (batch[mid] < b) lo = mid + 1; else hi = mid; }
        sb[0] = lo;
        int lo2 = lo, hi2 = n;
        while (lo2 < hi2) { int mid = (lo2 + hi2) >> 1; if (batch[mid] < b + 1) lo2 = mid + 1; else hi2 = mid; }
        sb[1] = lo2;
    }
    __syncthreads();
    int lo = sb[0], hi = sb[1];
    int c = t & 31, g = t >> 5; // 8 groups of 32
    float acc = 0.f;
    for (int i = lo + g; i < hi; i += 8) acc += h2[(size_t)i * 32 + c];
    __shared__ float red[8][32];
    __shared__ float sp[32], so[128];
    red[g][c] = acc;
    __syncthreads();
    if (t < 32) {
        float s = 0.f;
#pragma unroll
        for (int g2 = 0; g2 < 8; ++g2) s += red[g2][t];
        float cnt = (float)(hi - lo);
        sp[t] = s / fmaxf(cnt, 1.f);
    }
    __syncthreads();
    if (t < 128) {
        float o = b_fp[t];
#pragma unroll 8
        for (int k = 0; k < 32; ++k) o += sp[k] * w_fp[k * 128 + t];
        so[t] = o;
    }
    __syncthreads();
    if (t < 64) {
        float hm = b_m1[t];
        for (int cc = 0; cc < 128; ++cc) hm += so[cc] * w_m1[cc * 64 + t];
        float v = fmaxf(hm, 0.f) * w_m2[t];
#pragma unroll
        for (int offd = 32; offd > 0; offd >>= 1) v += __shfl_down(v, offd);
        if (t == 0) out[b] = v + b_m2[0];
    }
}

extern "C" void kernel_launch(void* const* d_in, const int* in_sizes, int n_in,
                              void* d_out, int out_size, void* d_ws, size_t ws_size,
                              hipStream_t stream) {
    const float* x = (const float*)d_in[0];
    const int* ei = (const int*)d_in[1];
    const int* batch = (const int*)d_in[2];
    const float* w_in = (const float*)d_in[3];
    const float* b_in = (const float*)d_in[4];
    const float* w[3] = {(const float*)d_in[5], (const float*)d_in[9], (const float*)d_in[13]};
    const float* asrc[3] = {(const float*)d_in[6], (const float*)d_in[10], (const float*)d_in[14]};
    const float* adst[3] = {(const float*)d_in[7], (const float*)d_in[11], (const float*)d_in[15]};
    const float* bb[3] = {(const float*)d_in[8], (const float*)d_in[12], (const float*)d_in[16]};
    const float* w_fp = (const float*)d_in[17];
    const float* b_fp = (const float*)d_in[18];
    const float* w_m1 = (const float*)d_in[19];
    const float* b_m1 = (const float*)d_in[20];
    const float* w_m2 = (const float*)d_in[21];
    const float* b_m2 = (const float*)d_in[22];

    int n = in_sizes[0] / 128;
    int e = in_sizes[1] / 2;
    int B = out_size;
    int nk = n * NB;

    char* wsb = (char*)d_ws;
    size_t off = 0;
    auto alloc = [&](size_t bytes) -> void* {
        void* p = wsb + off;
        off += (bytes + 255) & ~(size_t)255;
        return p;
    };
    ushort* hAu = (ushort*)alloc((size_t)n * 128 * 2);  // proj out / agg concat out (bf16)
    ushort* hBu = (ushort*)alloc((size_t)n * 128 * 2);  // per-layer gemm out (bf16)
    float* h3 = (float*)alloc((size_t)n * 32 * 4);      // layer-3 agg out (fp32)
    float* als = (float*)alloc((size_t)n * 4 * 4);
    float* ald = (float*)alloc((size_t)n * 4 * 4);
    int* deg = (int*)alloc((size_t)nk * 4);             // reused as cursor
    int* rowp = (int*)alloc((size_t)(nk + 1) * 4);
    int* col = (int*)alloc((size_t)(e + 8) * 4);
    int* bsums = (int*)alloc(16384);
    ushort* whi = (ushort*)alloc((size_t)4 * 16384 * 2);
    ushort* wlo = (ushort*)alloc((size_t)4 * 16384 * 2);

    const int* srcp = ei;
    const int* dstp = ei + e;

    // bucketed CSR by (dst, src-bucket) — graph shared by all 3 layers
    hipMemsetAsync(deg, 0, (size_t)nk * 4, stream);
    hist_kernel<<<(e + 255) / 256, 256, 0, stream>>>(srcp, dstp, e, deg);
    int nb = (nk + 2047) / 2048;
    scan1_kernel<<<nb, 256, 0, stream>>>(deg, nk, rowp, bsums);
    scan3_kernel<<<nb, 256, 0, stream>>>(rowp, bsums, nk, e, deg);
    fill_kernel<<<(e + 255) / 256, 256, 0, stream>>>(srcp, dstp, e, deg, col);

    // pre-pack all 4 weight matrices into bf16 hi/lo MFMA fragment order
    wpack_kernel<<<256, 256, 0, stream>>>(w_in, w[0], w[1], w[2], whi, wlo);

    int ntiles = (n + 31) / 32;
    int gblk = ntiles < 512 ? ntiles : 512;

    // input projection (fp32 A split hi/lo, bias, bf16 out)
    gemm_mfma_kernel<true, false, false><<<gblk, 512, 0, stream>>>(
        x, whi, wlo, b_in, hAu, n, ntiles, nullptr, nullptr, nullptr, nullptr);

    // 3 GAT layers: mfma gemm hAu->hBu (bf16 A, +fused al), fused-exp aggregate
    int gridAgg = (n + 7) / 8; // 2 nodes/wave, 4 waves/block
    for (int L = 0; L < 3; ++L) {
        gemm_mfma_kernel<false, true, true><<<gblk, 512, 0, stream>>>(
            hAu, whi + (size_t)(L + 1) * 16384, wlo + (size_t)(L + 1) * 16384, nullptr, hBu, n,
            ntiles, asrc[L], adst[L], als, ald);
        if (L < 2)
            agg_kernel<true><<<gridAgg, 256, 0, stream>>>(hBu, als, ald, rowp, col, bb[L],
                                                          hAu, nullptr, n);
        else
            agg_kernel<false><<<gridAgg, 256, 0, stream>>>(hBu, als, ald, rowp, col, bb[L],
                                                           nullptr, h3, n);
    }

    // fused pooling + MLP head
    poolmlp_kernel<<<B, 256, 0, stream>>>(h3, batch, n, w_fp, b_fp, w_m1, b_m1, w_m2, b_m2,
                                          (float*)d_out);
}

// Round 9
// 301.688 us; speedup vs baseline: 1.3580x; 1.1661x over previous
//
#include <hip/hip_runtime.h>

#define NEG 0.2f

typedef short s16x8 __attribute__((ext_vector_type(8)));
typedef float f32x4 __attribute__((ext_vector_type(4)));

__device__ __forceinline__ float lrelu(float x) { return x >= 0.f ? x : NEG * x; }
__device__ __forceinline__ float elu1(float x) { return x > 0.f ? x : __expf(x) - 1.f; }

__device__ __forceinline__ unsigned bf16rn(float f) {
    unsigned u = __float_as_uint(f);
    u += 0x7fffu + ((u >> 16) & 1u);
    return u >> 16;
}
__device__ __forceinline__ float bf16tof(ushort h) {
    return __uint_as_float(((unsigned)h) << 16);
}
__device__ __forceinline__ float bf16lo(unsigned u) { return __uint_as_float(u << 16); }
__device__ __forceinline__ float bf16hi(unsigned u) { return __uint_as_float(u & 0xffff0000u); }

// ----------------- plain dst-CSR build -----------------
__global__ void hist_kernel(const int* __restrict__ dst, int e, int* __restrict__ deg) {
    int i = blockIdx.x * blockDim.x + threadIdx.x;
    if (i < e) atomicAdd(&deg[dst[i]], 1);
}

__device__ __forceinline__ int waveIncScanI(int v, int lane) {
#pragma unroll
    for (int off = 1; off < 64; off <<= 1) {
        int u = __shfl_up(v, off);
        if (lane >= off) v += u;
    }
    return v;
}

__global__ void scan1_kernel(const int* __restrict__ deg, int nk,
                             int* __restrict__ rowp, int* __restrict__ bsums) {
    int t = threadIdx.x;
    int base = blockIdx.x * 2048 + t * 8;
    int vals[8];
    int sum = 0;
#pragma unroll
    for (int i = 0; i < 8; ++i) {
        int idx = base + i;
        int v = (idx < nk) ? deg[idx] : 0;
        vals[i] = sum;
        sum += v;
    }
    int lane = t & 63, w = t >> 6;
    int inc = waveIncScanI(sum, lane);
    __shared__ int wsums[4];
    if (lane == 63) wsums[w] = inc;
    __syncthreads();
    int wpre = 0;
#pragma unroll
    for (int i = 0; i < 3; ++i) wpre += (i < w) ? wsums[i] : 0;
    int exc = wpre + inc - sum;
#pragma unroll
    for (int i = 0; i < 8; ++i) {
        int idx = base + i;
        if (idx < nk) rowp[idx] = exc + vals[i];
    }
    if (t == 255) bsums[blockIdx.x] = wpre + inc;
}

// scan3: per-block prefix computed locally from bsums (merged scan2), copy cursor
__global__ void scan3_kernel(int* __restrict__ rowp, const int* __restrict__ bsums,
                             int nk, int total, int* __restrict__ cursor) {
    int g = blockIdx.x;
    __shared__ int spre;
    if (threadIdx.x < 64) {
        int lane = threadIdx.x;
        int v = 0;
        for (int base = lane; base < g; base += 64) v += bsums[base];
#pragma unroll
        for (int off = 32; off > 0; off >>= 1) v += __shfl_xor(v, off);
        if (lane == 0) spre = v;
    }
    __syncthreads();
    int pre = spre;
    int base = g * 2048 + threadIdx.x * 8;
#pragma unroll
    for (int i = 0; i < 8; ++i) {
        int idx = base + i;
        if (idx < nk) {
            int v = rowp[idx] + pre;
            rowp[idx] = v;
            cursor[idx] = v;
        } else if (idx == nk) {
            rowp[nk] = total;
        }
    }
}

__global__ void fill_kernel(const int* __restrict__ src, const int* __restrict__ dst, int e,
                            int* __restrict__ cursor, int* __restrict__ col) {
    int i = blockIdx.x * blockDim.x + threadIdx.x;
    if (i < e) {
        int s = src[i], d = dst[i];
        int pos = atomicAdd(&cursor[d], 1);
        col[pos] = s;
    }
}

// ----------------- W pre-pack: fp32 [128][128] -> bf16 hi/lo in MFMA B-frag order
__global__ void wpack_kernel(const float* __restrict__ w0, const float* __restrict__ w1,
                             const float* __restrict__ w2, const float* __restrict__ w3,
                             ushort* __restrict__ whi, ushort* __restrict__ wlo) {
    int idx = blockIdx.x * 256 + threadIdx.x; // 4*16384
    int layer = idx >> 14, e = idx & 16383;
    const float* W = layer == 0 ? w0 : layer == 1 ? w1 : layer == 2 ? w2 : w3;
    int k = e >> 7, c = e & 127;
    float w = W[e];
    ushort hi = (ushort)bf16rn(w);
    ushort lo = (ushort)bf16rn(w - bf16tof(hi));
    int kt = k >> 5, kk = k & 31, j = kk & 7;
    int ln = ((kk >> 3) << 4) | (c & 15);
    int ntg = c >> 4;
    int pos = (layer << 14) + (((kt << 3) + ntg) * 64 + ln) * 8 + j;
    whi[pos] = hi;
    wlo[pos] = lo;
}

// ----------------- MFMA split-bf16 GEMM: out[n,128](bf16) = A[n,128] @ W[128,128]
// ABF16: A rows are bf16 (exact) -> 4 MFMAs/kt; else fp32 A split hi/lo -> 6 MFMAs/kt.
template <bool BIAS, bool AL, bool ABF16>
__global__ __launch_bounds__(512, 4) void gemm_mfma_kernel(
    const void* __restrict__ Av, const ushort* __restrict__ whi, const ushort* __restrict__ wlo,
    const float* __restrict__ bias, ushort* __restrict__ outb, int n, int ntiles,
    const float* __restrict__ asrc, const float* __restrict__ adst,
    float* __restrict__ als, float* __restrict__ ald) {
    __shared__ s16x8 ahi[2][4][64];
    __shared__ s16x8 alo[2][4][64];
    int t = threadIdx.x;
    int wid = t >> 6, lane = t & 63;
    int ntp = wid & 3;    // head / 32-col pair
    int mhalf = wid >> 2; // which 16-row half

    const s16x8* wph = (const s16x8*)whi;
    const s16x8* wpl = (const s16x8*)wlo;
    s16x8 wh[4][2], wl[4][2];
#pragma unroll
    for (int kt = 0; kt < 4; ++kt)
#pragma unroll
        for (int j = 0; j < 2; ++j) {
            int ntg = ntp * 2 + j;
            wh[kt][j] = wph[((kt << 3) + ntg) * 64 + lane];
            wl[kt][j] = wpl[((kt << 3) + ntg) * 64 + lane];
        }

    int c0 = ntp * 32 + (lane & 15);
    int c1 = c0 + 16;
    float bv0 = 0.f, bv1 = 0.f;
    if (BIAS) { bv0 = bias[c0]; bv1 = bias[c1]; }
    float as0 = 0.f, as1 = 0.f, ad0 = 0.f, ad1 = 0.f;
    if (AL) {
        as0 = asrc[ntp * 32 + (lane & 15)];
        as1 = asrc[ntp * 32 + 16 + (lane & 15)];
        ad0 = adst[ntp * 32 + (lane & 15)];
        ad1 = adst[ntp * 32 + 16 + (lane & 15)];
    }

    int srow = t >> 4, skoct = t & 15;
    int smh = srow >> 4, skt = skoct >> 2;
    int sln = ((skoct & 3) << 4) | (srow & 15);

    for (int tile = blockIdx.x; tile < ntiles; tile += gridDim.x) {
        int r0 = tile * 32;
        {
            int gr = r0 + srow;
            if (ABF16) {
                const ushort* Ab = (const ushort*)Av;
                s16x8 hi = {0, 0, 0, 0, 0, 0, 0, 0};
                if (gr < n) hi = *(const s16x8*)(Ab + (size_t)gr * 128 + skoct * 8);
                ahi[smh][skt][sln] = hi;
            } else {
                const float* Af = (const float*)Av;
                float4 v0 = make_float4(0.f, 0.f, 0.f, 0.f), v1 = v0;
                if (gr < n) {
                    const float4* rp = (const float4*)(Af + (size_t)gr * 128 + skoct * 8);
                    v0 = rp[0];
                    v1 = rp[1];
                }
                float f[8] = {v0.x, v0.y, v0.z, v0.w, v1.x, v1.y, v1.z, v1.w};
                s16x8 hi, lo;
#pragma unroll
                for (int j = 0; j < 8; ++j) {
                    ushort h = (ushort)bf16rn(f[j]);
                    hi[j] = (short)h;
                    lo[j] = (short)bf16rn(f[j] - bf16tof(h));
                }
                ahi[smh][skt][sln] = hi;
                alo[smh][skt][sln] = lo;
            }
        }
        __syncthreads();

        f32x4 acc0 = {0.f, 0.f, 0.f, 0.f};
        f32x4 acc1 = {0.f, 0.f, 0.f, 0.f};
#pragma unroll
        for (int kt = 0; kt < 4; ++kt) {
            s16x8 ah = ahi[mhalf][kt][lane];
            if (ABF16) {
                acc0 = __builtin_amdgcn_mfma_f32_16x16x32_bf16(ah, wh[kt][0], acc0, 0, 0, 0);
                acc0 = __builtin_amdgcn_mfma_f32_16x16x32_bf16(ah, wl[kt][0], acc0, 0, 0, 0);
                acc1 = __builtin_amdgcn_mfma_f32_16x16x32_bf16(ah, wh[kt][1], acc1, 0, 0, 0);
                acc1 = __builtin_amdgcn_mfma_f32_16x16x32_bf16(ah, wl[kt][1], acc1, 0, 0, 0);
            } else {
                s16x8 al = alo[mhalf][kt][lane];
                acc0 = __builtin_amdgcn_mfma_f32_16x16x32_bf16(ah, wh[kt][0], acc0, 0, 0, 0);
                acc0 = __builtin_amdgcn_mfma_f32_16x16x32_bf16(ah, wl[kt][0], acc0, 0, 0, 0);
                acc0 = __builtin_amdgcn_mfma_f32_16x16x32_bf16(al, wh[kt][0], acc0, 0, 0, 0);
                acc1 = __builtin_amdgcn_mfma_f32_16x16x32_bf16(ah, wh[kt][1], acc1, 0, 0, 0);
                acc1 = __builtin_amdgcn_mfma_f32_16x16x32_bf16(ah, wl[kt][1], acc1, 0, 0, 0);
                acc1 = __builtin_amdgcn_mfma_f32_16x16x32_bf16(al, wh[kt][1], acc1, 0, 0, 0);
            }
        }

        int rbase = r0 + mhalf * 16 + (lane >> 4) * 4;
#pragma unroll
        for (int i = 0; i < 4; ++i) {
            int r = rbase + i;
            if (r < n) {
                outb[(size_t)r * 128 + c0] = (ushort)bf16rn(acc0[i] + bv0);
                outb[(size_t)r * 128 + c1] = (ushort)bf16rn(acc1[i] + bv1);
            }
        }
        if (AL) {
#pragma unroll
            for (int i = 0; i < 4; ++i) {
                float ps = acc0[i] * as0 + acc1[i] * as1;
                float pd = acc0[i] * ad0 + acc1[i] * ad1;
                ps += __shfl_xor(ps, 1); ps += __shfl_xor(ps, 2);
                ps += __shfl_xor(ps, 4); ps += __shfl_xor(ps, 8);
                pd += __shfl_xor(pd, 1); pd += __shfl_xor(pd, 2);
                pd += __shfl_xor(pd, 4); pd += __shfl_xor(pd, 8);
                int r = rbase + i;
                if ((lane & 15) == 0 && r < n) {
                    als[r * 4 + ntp] = ps;
                    ald[r * 4 + ntp] = pd;
                }
            }
        }
        __syncthreads();
    }
}

// ----------------- GAT aggregation: TWO nodes per wave (32 lanes / 4 channels each);
// exp(lrelu(..)) computed in-kernel by lane specialization (j=slot, hh=head) + shfl;
// bf16 rows; inline self-loop -----------------
template <bool CONCAT>
__global__ void agg_kernel(const ushort* __restrict__ hp, const float* __restrict__ als,
                           const float* __restrict__ ald_, const int* __restrict__ rowp,
                           const int* __restrict__ col, const float* __restrict__ bias,
                           ushort* __restrict__ outb, float* __restrict__ outf, int n) {
    int lane = threadIdx.x & 63;
    int hl = lane & 31;   // lane within half-wave
    int wid = (blockIdx.x * blockDim.x + threadIdx.x) >> 6;
    int d = wid * 2 + (lane >> 5);
    bool valid = d < n;
    int dc = valid ? d : (n - 1);

    int h = hl >> 3;      // data head (this lane's 4 channels)
    int c4 = hl * 4;      // channel base 0..124
    int hh = hl & 3;      // exp-duty head
    int jl = hl >> 2;     // exp-duty edge slot 0..7
    int bshf = lane & 32; // half base for shuffles

    int start = rowp[dc];
    int end = valid ? rowp[dc + 1] : start;

    float aldv_hh = ald_[dc * 4 + hh];
    float eself = __expf(lrelu(als[dc * 4 + h] + ald_[dc * 4 + h]));

    uint2 sv = *(const uint2*)(hp + (size_t)dc * 128 + c4);
    float a0 = eself * bf16lo(sv.x), a1 = eself * bf16hi(sv.x);
    float a2 = eself * bf16lo(sv.y), a3 = eself * bf16hi(sv.y);
    float esum = eself;

    int iters = (end - start + 7) >> 3;
    int oiters = __shfl_xor(iters, 32);
    int maxit = iters > oiters ? iters : oiters;
    unsigned nclamp = (unsigned)(n - 1);

    for (int it = 0; it < maxit; ++it) {
        int p0 = start + it * 8;
        bool act = p0 < end;
        int pc = act ? p0 : start;
        int4 ca = *(const int4*)(col + pc);
        int4 cb = *(const int4*)(col + pc + 4);
        // exp duty: this lane's (edge jl, head hh)
        unsigned se = (unsigned)col[pc + jl];
        se = se > nclamp ? nclamp : se;
        float ee = __expf(lrelu(als[(size_t)se * 4 + hh] + aldv_hh));
        ee = (act && (p0 + jl < end)) ? ee : 0.f;

#define EDGE(JJ, SRC)                                                              \
        {                                                                          \
            float ej = __shfl(ee, bshf | (JJ << 2) | h);                           \
            unsigned sju = (unsigned)(SRC);                                        \
            sju = sju > nclamp ? nclamp : sju;                                     \
            uint2 uv = *(const uint2*)(hp + (size_t)sju * 128 + c4);               \
            a0 += ej * bf16lo(uv.x); a1 += ej * bf16hi(uv.x);                      \
            a2 += ej * bf16lo(uv.y); a3 += ej * bf16hi(uv.y);                      \
            esum += ej;                                                            \
        }
        EDGE(0, ca.x) EDGE(1, ca.y) EDGE(2, ca.z) EDGE(3, ca.w)
        EDGE(4, cb.x) EDGE(5, cb.y) EDGE(6, cb.z) EDGE(7, cb.w)
#undef EDGE
    }

    float inv = 1.f / (esum + 1e-16f);
    a0 *= inv; a1 *= inv; a2 *= inv; a3 *= inv;
    if (CONCAT) {
        if (valid) {
            float o0 = elu1(a0 + bias[c4]);
            float o1 = elu1(a1 + bias[c4 + 1]);
            float o2 = elu1(a2 + bias[c4 + 2]);
            float o3 = elu1(a3 + bias[c4 + 3]);
            uint2 pk;
            pk.x = bf16rn(o0) | (bf16rn(o1) << 16);
            pk.y = bf16rn(o2) | (bf16rn(o3) << 16);
            *(uint2*)(outb + (size_t)d * 128 + c4) = pk;
        }
    } else {
        // mean over 4 heads: lanes {hl, hl^8, hl^16, hl^24} share channel-in-head
        a0 += __shfl_xor(a0, 8); a0 += __shfl_xor(a0, 16);
        a1 += __shfl_xor(a1, 8); a1 += __shfl_xor(a1, 16);
        a2 += __shfl_xor(a2, 8); a2 += __shfl_xor(a2, 16);
        a3 += __shfl_xor(a3, 8); a3 += __shfl_xor(a3, 16);
        if (valid && hl < 8) {
            int cin = hl * 4;
            float4 o;
            o.x = elu1(a0 * 0.25f + bias[cin]);
            o.y = elu1(a1 * 0.25f + bias[cin + 1]);
            o.z = elu1(a2 * 0.25f + bias[cin + 2]);
            o.w = elu1(a3 * 0.25f + bias[cin + 3]);
            *(float4*)(outf + (size_t)d * 32 + cin) = o;
        }
    }
}

// ----------------- fused mean-pool + final_proj + MLP head, one block per batch row ---------
__global__ void poolmlp_kernel(const float* __restrict__ h2, const int* __restrict__ batch,
                               int n, const float* __restrict__ w_fp,
                               const float* __restrict__ b_fp, const float* __restrict__ w_m1,
                               const float* __restrict__ b_m1, const float* __restrict__ w_m2,
                               const float* __restrict__ b_m2, float* __restrict__ out) {
    int b = blockIdx.x, t = threadIdx.x; // 256 threads
    __shared__ int sb[2];
    if (t == 0) {
        int lo = 0, hi = n;
        while (lo < hi) { int mid = (lo + hi) >> 1; if (batch[mid] < b) lo = mid + 1; else hi = mid; }
        sb[0] = lo;
        int lo2 = lo, hi2 = n;
        while (lo2 < hi2) { int mid = (lo2 + hi2) >> 1; if (batch[mid] < b + 1) lo2 = mid + 1; else hi2 = mid; }
        sb[1] = lo2;
    }
    __syncthreads();
    int lo = sb[0], hi = sb[1];
    int c = t & 31, g = t >> 5; // 8 groups of 32
    float acc = 0.f;
    for (int i = lo + g; i < hi; i += 8) acc += h2[(size_t)i * 32 + c];
    __shared__ float red[8][32];
    __shared__ float sp[32], so[128];
    red[g][c] = acc;
    __syncthreads();
    if (t < 32) {
        float s = 0.f;
#pragma unroll
        for (int g2 = 0; g2 < 8; ++g2) s += red[g2][t];
        float cnt = (float)(hi - lo);
        sp[t] = s / fmaxf(cnt, 1.f);
    }
    __syncthreads();
    if (t < 128) {
        float o = b_fp[t];
#pragma unroll 8
        for (int k = 0; k < 32; ++k) o += sp[k] * w_fp[k * 128 + t];
        so[t] = o;
    }
    __syncthreads();
    if (t < 64) {
        float hm = b_m1[t];
        for (int cc = 0; cc < 128; ++cc) hm += so[cc] * w_m1[cc * 64 + t];
        float v = fmaxf(hm, 0.f) * w_m2[t];
#pragma unroll
        for (int offd = 32; offd > 0; offd >>= 1) v += __shfl_down(v, offd);
        if (t == 0) out[b] = v + b_m2[0];
    }
}

extern "C" void kernel_launch(void* const* d_in, const int* in_sizes, int n_in,
                              void* d_out, int out_size, void* d_ws, size_t ws_size,
                              hipStream_t stream) {
    const float* x = (const float*)d_in[0];
    const int* ei = (const int*)d_in[1];
    const int* batch = (const int*)d_in[2];
    const float* w_in = (const float*)d_in[3];
    const float* b_in = (const float*)d_in[4];
    const float* w[3] = {(const float*)d_in[5], (const float*)d_in[9], (const float*)d_in[13]};
    const float* asrc[3] = {(const float*)d_in[6], (const float*)d_in[10], (const float*)d_in[14]};
    const float* adst[3] = {(const float*)d_in[7], (const float*)d_in[11], (const float*)d_in[15]};
    const float* bb[3] = {(const float*)d_in[8], (const float*)d_in[12], (const float*)d_in[16]};
    const float* w_fp = (const float*)d_in[17];
    const float* b_fp = (const float*)d_in[18];
    const float* w_m1 = (const float*)d_in[19];
    const float* b_m1 = (const float*)d_in[20];
    const float* w_m2 = (const float*)d_in[21];
    const float* b_m2 = (const float*)d_in[22];

    int n = in_sizes[0] / 128;
    int e = in_sizes[1] / 2;
    int B = out_size;

    char* wsb = (char*)d_ws;
    size_t off = 0;
    auto alloc = [&](size_t bytes) -> void* {
        void* p = wsb + off;
        off += (bytes + 255) & ~(size_t)255;
        return p;
    };
    ushort* hAu = (ushort*)alloc((size_t)n * 128 * 2);  // proj out / agg concat out (bf16)
    ushort* hBu = (ushort*)alloc((size_t)n * 128 * 2);  // per-layer gemm out (bf16)
    float* h3 = (float*)alloc((size_t)n * 32 * 4);      // layer-3 agg out (fp32)
    float* als = (float*)alloc((size_t)n * 4 * 4);
    float* ald = (float*)alloc((size_t)n * 4 * 4);
    int* deg = (int*)alloc((size_t)n * 4);              // reused as cursor
    int* rowp = (int*)alloc((size_t)(n + 1) * 4);
    int* col = (int*)alloc((size_t)(e + 8) * 4);
    int* bsums = (int*)alloc(4096);
    ushort* whi = (ushort*)alloc((size_t)4 * 16384 * 2);
    ushort* wlo = (ushort*)alloc((size_t)4 * 16384 * 2);

    const int* srcp = ei;
    const int* dstp = ei + e;

    // plain dst-CSR — graph shared by all 3 layers
    hipMemsetAsync(deg, 0, (size_t)n * 4, stream);
    hist_kernel<<<(e + 255) / 256, 256, 0, stream>>>(dstp, e, deg);
    int nb = (n + 2047) / 2048;
    scan1_kernel<<<nb, 256, 0, stream>>>(deg, n, rowp, bsums);
    scan3_kernel<<<nb, 256, 0, stream>>>(rowp, bsums, n, e, deg);
    fill_kernel<<<(e + 255) / 256, 256, 0, stream>>>(srcp, dstp, e, deg, col);

    // pre-pack all 4 weight matrices into bf16 hi/lo MFMA fragment order
    wpack_kernel<<<256, 256, 0, stream>>>(w_in, w[0], w[1], w[2], whi, wlo);

    int ntiles = (n + 31) / 32;
    int gblk = ntiles < 512 ? ntiles : 512;

    // input projection (fp32 A split hi/lo, bias, bf16 out)
    gemm_mfma_kernel<true, false, false><<<gblk, 512, 0, stream>>>(
        x, whi, wlo, b_in, hAu, n, ntiles, nullptr, nullptr, nullptr, nullptr);

    // 3 GAT layers: mfma gemm hAu->hBu (bf16 A, +fused al), fused-exp aggregate
    int gridAgg = (n + 7) / 8; // 2 nodes/wave, 4 waves/block
    for (int L = 0; L < 3; ++L) {
        gemm_mfma_kernel<false, true, true><<<gblk, 512, 0, stream>>>(
            hAu, whi + (size_t)(L + 1) * 16384, wlo + (size_t)(L + 1) * 16384, nullptr, hBu, n,
            ntiles, asrc[L], adst[L], als, ald);
        if (L < 2)
            agg_kernel<true><<<gridAgg, 256, 0, stream>>>(hBu, als, ald, rowp, col, bb[L],
                                                          hAu, nullptr, n);
        else
            agg_kernel<false><<<gridAgg, 256, 0, stream>>>(hBu, als, ald, rowp, col, bb[L],
                                                           nullptr, h3, n);
    }

    // fused pooling + MLP head
    poolmlp_kernel<<<B, 256, 0, stream>>>(h3, batch, n, w_fp, b_fp, w_m1, b_m1, w_m2, b_m2,
                                          (float*)d_out);
}

// Round 10
// 296.217 us; speedup vs baseline: 1.3830x; 1.0185x over previous
//
#include <hip/hip_runtime.h>

#define NEG 0.2f

typedef short s16x8 __attribute__((ext_vector_type(8)));
typedef float f32x4 __attribute__((ext_vector_type(4)));

__device__ __forceinline__ float lrelu(float x) { return x >= 0.f ? x : NEG * x; }
__device__ __forceinline__ float elu1(float x) { return x > 0.f ? x : __expf(x) - 1.f; }

__device__ __forceinline__ unsigned bf16rn(float f) {
    unsigned u = __float_as_uint(f);
    u += 0x7fffu + ((u >> 16) & 1u);
    return u >> 16;
}
__device__ __forceinline__ float bf16tof(ushort h) {
    return __uint_as_float(((unsigned)h) << 16);
}
__device__ __forceinline__ float bf16lo(unsigned u) { return __uint_as_float(u << 16); }
__device__ __forceinline__ float bf16hi(unsigned u) { return __uint_as_float(u & 0xffff0000u); }

// ----------------- XCD-partitioned dst-CSR build -----------------
// blocks with blockIdx%8==p handle dst range p (lands on XCD p via round-robin dispatch):
// deg/cursor/col lines for a range are touched by ONE XCD -> L2-local atomics, 1x writeback.
__global__ void hist_kernel(const int* __restrict__ dst, int e, int n, int* __restrict__ deg) {
    int p = blockIdx.x & 7;
    int s = blockIdx.x >> 3;
    int nslices = gridDim.x >> 3;
    int rng = (n + 7) >> 3;
    int lo = p * rng, hi = min(n, lo + rng);
    int chunk = (e + nslices - 1) / nslices;
    int i0 = s * chunk, i1 = min(e, i0 + chunk);
    for (int i = i0 + threadIdx.x; i < i1; i += blockDim.x) {
        int d = dst[i];
        if (d >= lo && d < hi) atomicAdd(&deg[d], 1);
    }
}

__device__ __forceinline__ int waveIncScanI(int v, int lane) {
#pragma unroll
    for (int off = 1; off < 64; off <<= 1) {
        int u = __shfl_up(v, off);
        if (lane >= off) v += u;
    }
    return v;
}

__global__ void scan1_kernel(const int* __restrict__ deg, int nk,
                             int* __restrict__ rowp, int* __restrict__ bsums) {
    int t = threadIdx.x;
    int base = blockIdx.x * 2048 + t * 8;
    int vals[8];
    int sum = 0;
#pragma unroll
    for (int i = 0; i < 8; ++i) {
        int idx = base + i;
        int v = (idx < nk) ? deg[idx] : 0;
        vals[i] = sum;
        sum += v;
    }
    int lane = t & 63, w = t >> 6;
    int inc = waveIncScanI(sum, lane);
    __shared__ int wsums[4];
    if (lane == 63) wsums[w] = inc;
    __syncthreads();
    int wpre = 0;
#pragma unroll
    for (int i = 0; i < 3; ++i) wpre += (i < w) ? wsums[i] : 0;
    int exc = wpre + inc - sum;
#pragma unroll
    for (int i = 0; i < 8; ++i) {
        int idx = base + i;
        if (idx < nk) rowp[idx] = exc + vals[i];
    }
    if (t == 255) bsums[blockIdx.x] = wpre + inc;
}

// scan3: per-block prefix computed locally from bsums (merged scan2), copy cursor
__global__ void scan3_kernel(int* __restrict__ rowp, const int* __restrict__ bsums,
                             int nk, int total, int* __restrict__ cursor) {
    int g = blockIdx.x;
    __shared__ int spre;
    if (threadIdx.x < 64) {
        int lane = threadIdx.x;
        int v = 0;
        for (int base = lane; base < g; base += 64) v += bsums[base];
#pragma unroll
        for (int off = 32; off > 0; off >>= 1) v += __shfl_xor(v, off);
        if (lane == 0) spre = v;
    }
    __syncthreads();
    int pre = spre;
    int base = g * 2048 + threadIdx.x * 8;
#pragma unroll
    for (int i = 0; i < 8; ++i) {
        int idx = base + i;
        if (idx < nk) {
            int v = rowp[idx] + pre;
            rowp[idx] = v;
            cursor[idx] = v;
        } else if (idx == nk) {
            rowp[nk] = total;
        }
    }
}

__global__ void fill_kernel(const int* __restrict__ src, const int* __restrict__ dst, int e,
                            int n, int* __restrict__ cursor, int* __restrict__ col) {
    int p = blockIdx.x & 7;
    int s = blockIdx.x >> 3;
    int nslices = gridDim.x >> 3;
    int rng = (n + 7) >> 3;
    int lo = p * rng, hi = min(n, lo + rng);
    int chunk = (e + nslices - 1) / nslices;
    int i0 = s * chunk, i1 = min(e, i0 + chunk);
    for (int i = i0 + threadIdx.x; i < i1; i += blockDim.x) {
        int d = dst[i];
        if (d >= lo && d < hi) {
            int pos = atomicAdd(&cursor[d], 1);
            col[pos] = src[i];
        }
    }
}

// ----------------- W pre-pack: fp32 [128][128] -> bf16 hi/lo in MFMA B-frag order
__global__ void wpack_kernel(const float* __restrict__ w0, const float* __restrict__ w1,
                             const float* __restrict__ w2, const float* __restrict__ w3,
                             ushort* __restrict__ whi, ushort* __restrict__ wlo) {
    int idx = blockIdx.x * 256 + threadIdx.x; // 4*16384
    int layer = idx >> 14, e = idx & 16383;
    const float* W = layer == 0 ? w0 : layer == 1 ? w1 : layer == 2 ? w2 : w3;
    int k = e >> 7, c = e & 127;
    float w = W[e];
    ushort hi = (ushort)bf16rn(w);
    ushort lo = (ushort)bf16rn(w - bf16tof(hi));
    int kt = k >> 5, kk = k & 31, j = kk & 7;
    int ln = ((kk >> 3) << 4) | (c & 15);
    int ntg = c >> 4;
    int pos = (layer << 14) + (((kt << 3) + ntg) * 64 + ln) * 8 + j;
    whi[pos] = hi;
    wlo[pos] = lo;
}

// ----------------- MFMA split-bf16 GEMM: out[n,128](bf16) = A[n,128] @ W[128,128]
// ABF16: A rows are bf16 (exact) -> 4 MFMAs/kt; else fp32 A split hi/lo -> 6 MFMAs/kt.
template <bool BIAS, bool AL, bool ABF16>
__global__ __launch_bounds__(512, 4) void gemm_mfma_kernel(
    const void* __restrict__ Av, const ushort* __restrict__ whi, const ushort* __restrict__ wlo,
    const float* __restrict__ bias, ushort* __restrict__ outb, int n, int ntiles,
    const float* __restrict__ asrc, const float* __restrict__ adst,
    float* __restrict__ als, float* __restrict__ ald) {
    __shared__ s16x8 ahi[2][4][64];
    __shared__ s16x8 alo[2][4][64];
    int t = threadIdx.x;
    int wid = t >> 6, lane = t & 63;
    int ntp = wid & 3;    // head / 32-col pair
    int mhalf = wid >> 2; // which 16-row half

    const s16x8* wph = (const s16x8*)whi;
    const s16x8* wpl = (const s16x8*)wlo;
    s16x8 wh[4][2], wl[4][2];
#pragma unroll
    for (int kt = 0; kt < 4; ++kt)
#pragma unroll
        for (int j = 0; j < 2; ++j) {
            int ntg = ntp * 2 + j;
            wh[kt][j] = wph[((kt << 3) + ntg) * 64 + lane];
            wl[kt][j] = wpl[((kt << 3) + ntg) * 64 + lane];
        }

    int c0 = ntp * 32 + (lane & 15);
    int c1 = c0 + 16;
    float bv0 = 0.f, bv1 = 0.f;
    if (BIAS) { bv0 = bias[c0]; bv1 = bias[c1]; }
    float as0 = 0.f, as1 = 0.f, ad0 = 0.f, ad1 = 0.f;
    if (AL) {
        as0 = asrc[ntp * 32 + (lane & 15)];
        as1 = asrc[ntp * 32 + 16 + (lane & 15)];
        ad0 = adst[ntp * 32 + (lane & 15)];
        ad1 = adst[ntp * 32 + 16 + (lane & 15)];
    }

    int srow = t >> 4, skoct = t & 15;
    int smh = srow >> 4, skt = skoct >> 2;
    int sln = ((skoct & 3) << 4) | (srow & 15);

    for (int tile = blockIdx.x; tile < ntiles; tile += gridDim.x) {
        int r0 = tile * 32;
        {
            int gr = r0 + srow;
            if (ABF16) {
                const ushort* Ab = (const ushort*)Av;
                s16x8 hi = {0, 0, 0, 0, 0, 0, 0, 0};
                if (gr < n) hi = *(const s16x8*)(Ab + (size_t)gr * 128 + skoct * 8);
                ahi[smh][skt][sln] = hi;
            } else {
                const float* Af = (const float*)Av;
                float4 v0 = make_float4(0.f, 0.f, 0.f, 0.f), v1 = v0;
                if (gr < n) {
                    const float4* rp = (const float4*)(Af + (size_t)gr * 128 + skoct * 8);
                    v0 = rp[0];
                    v1 = rp[1];
                }
                float f[8] = {v0.x, v0.y, v0.z, v0.w, v1.x, v1.y, v1.z, v1.w};
                s16x8 hi, lo;
#pragma unroll
                for (int j = 0; j < 8; ++j) {
                    ushort h = (ushort)bf16rn(f[j]);
                    hi[j] = (short)h;
                    lo[j] = (short)bf16rn(f[j] - bf16tof(h));
                }
                ahi[smh][skt][sln] = hi;
                alo[smh][skt][sln] = lo;
            }
        }
        __syncthreads();

        f32x4 acc0 = {0.f, 0.f, 0.f, 0.f};
        f32x4 acc1 = {0.f, 0.f, 0.f, 0.f};
#pragma unroll
        for (int kt = 0; kt < 4; ++kt) {
            s16x8 ah = ahi[mhalf][kt][lane];
            if (ABF16) {
                acc0 = __builtin_amdgcn_mfma_f32_16x16x32_bf16(ah, wh[kt][0], acc0, 0, 0, 0);
                acc0 = __builtin_amdgcn_mfma_f32_16x16x32_bf16(ah, wl[kt][0], acc0, 0, 0, 0);
                acc1 = __builtin_amdgcn_mfma_f32_16x16x32_bf16(ah, wh[kt][1], acc1, 0, 0, 0);
                acc1 = __builtin_amdgcn_mfma_f32_16x16x32_bf16(ah, wl[kt][1], acc1, 0, 0, 0);
            } else {
                s16x8 al = alo[mhalf][kt][lane];
                acc0 = __builtin_amdgcn_mfma_f32_16x16x32_bf16(ah, wh[kt][0], acc0, 0, 0, 0);
                acc0 = __builtin_amdgcn_mfma_f32_16x16x32_bf16(ah, wl[kt][0], acc0, 0, 0, 0);
                acc0 = __builtin_amdgcn_mfma_f32_16x16x32_bf16(al, wh[kt][0], acc0, 0, 0, 0);
                acc1 = __builtin_amdgcn_mfma_f32_16x16x32_bf16(ah, wh[kt][1], acc1, 0, 0, 0);
                acc1 = __builtin_amdgcn_mfma_f32_16x16x32_bf16(ah, wl[kt][1], acc1, 0, 0, 0);
                acc1 = __builtin_amdgcn_mfma_f32_16x16x32_bf16(al, wh[kt][1], acc1, 0, 0, 0);
            }
        }

        int rbase = r0 + mhalf * 16 + (lane >> 4) * 4;
#pragma unroll
        for (int i = 0; i < 4; ++i) {
            int r = rbase + i;
            if (r < n) {
                outb[(size_t)r * 128 + c0] = (ushort)bf16rn(acc0[i] + bv0);
                outb[(size_t)r * 128 + c1] = (ushort)bf16rn(acc1[i] + bv1);
            }
        }
        if (AL) {
#pragma unroll
            for (int i = 0; i < 4; ++i) {
                float ps = acc0[i] * as0 + acc1[i] * as1;
                float pd = acc0[i] * ad0 + acc1[i] * ad1;
                ps += __shfl_xor(ps, 1); ps += __shfl_xor(ps, 2);
                ps += __shfl_xor(ps, 4); ps += __shfl_xor(ps, 8);
                pd += __shfl_xor(pd, 1); pd += __shfl_xor(pd, 2);
                pd += __shfl_xor(pd, 4); pd += __shfl_xor(pd, 8);
                int r = rbase + i;
                if ((lane & 15) == 0 && r < n) {
                    als[r * 4 + ntp] = ps;
                    ald[r * 4 + ntp] = pd;
                }
            }
        }
        __syncthreads();
    }
}

// ----------------- GAT aggregation: TWO nodes per wave (32 lanes / 4 channels each);
// exp(lrelu(..)) computed in-kernel by lane specialization (j=slot, hh=head) + shfl;
// bf16 rows; inline self-loop -----------------
template <bool CONCAT>
__global__ void agg_kernel(const ushort* __restrict__ hp, const float* __restrict__ als,
                           const float* __restrict__ ald_, const int* __restrict__ rowp,
                           const int* __restrict__ col, const float* __restrict__ bias,
                           ushort* __restrict__ outb, float* __restrict__ outf, int n) {
    int lane = threadIdx.x & 63;
    int hl = lane & 31;   // lane within half-wave
    int wid = (blockIdx.x * blockDim.x + threadIdx.x) >> 6;
    int d = wid * 2 + (lane >> 5);
    bool valid = d < n;
    int dc = valid ? d : (n - 1);

    int h = hl >> 3;      // data head (this lane's 4 channels)
    int c4 = hl * 4;      // channel base 0..124
    int hh = hl & 3;      // exp-duty head
    int jl = hl >> 2;     // exp-duty edge slot 0..7
    int bshf = lane & 32; // half base for shuffles

    int start = rowp[dc];
    int end = valid ? rowp[dc + 1] : start;

    float aldv_hh = ald_[dc * 4 + hh];
    float eself = __expf(lrelu(als[dc * 4 + h] + ald_[dc * 4 + h]));

    uint2 sv = *(const uint2*)(hp + (size_t)dc * 128 + c4);
    float a0 = eself * bf16lo(sv.x), a1 = eself * bf16hi(sv.x);
    float a2 = eself * bf16lo(sv.y), a3 = eself * bf16hi(sv.y);
    float esum = eself;

    int iters = (end - start + 7) >> 3;
    int oiters = __shfl_xor(iters, 32);
    int maxit = iters > oiters ? iters : oiters;
    unsigned nclamp = (unsigned)(n - 1);

    for (int it = 0; it < maxit; ++it) {
        int p0 = start + it * 8;
        bool act = p0 < end;
        int pc = act ? p0 : start;
        int4 ca = *(const int4*)(col + pc);
        int4 cb = *(const int4*)(col + pc + 4);
        // exp duty: this lane's (edge jl, head hh)
        unsigned se = (unsigned)col[pc + jl];
        se = se > nclamp ? nclamp : se;
        float ee = __expf(lrelu(als[(size_t)se * 4 + hh] + aldv_hh));
        ee = (act && (p0 + jl < end)) ? ee : 0.f;

#define EDGE(JJ, SRC)                                                              \
        {                                                                          \
            float ej = __shfl(ee, bshf | (JJ << 2) | h);                           \
            unsigned sju = (unsigned)(SRC);                                        \
            sju = sju > nclamp ? nclamp : sju;                                     \
            uint2 uv = *(const uint2*)(hp + (size_t)sju * 128 + c4);               \
            a0 += ej * bf16lo(uv.x); a1 += ej * bf16hi(uv.x);                      \
            a2 += ej * bf16lo(uv.y); a3 += ej * bf16hi(uv.y);                      \
            esum += ej;                                                            \
        }
        EDGE(0, ca.x) EDGE(1, ca.y) EDGE(2, ca.z) EDGE(3, ca.w)
        EDGE(4, cb.x) EDGE(5, cb.y) EDGE(6, cb.z) EDGE(7, cb.w)
#undef EDGE
    }

    float inv = 1.f / (esum + 1e-16f);
    a0 *= inv; a1 *= inv; a2 *= inv; a3 *= inv;
    if (CONCAT) {
        if (valid) {
            float o0 = elu1(a0 + bias[c4]);
            float o1 = elu1(a1 + bias[c4 + 1]);
            float o2 = elu1(a2 + bias[c4 + 2]);
            float o3 = elu1(a3 + bias[c4 + 3]);
            uint2 pk;
            pk.x = bf16rn(o0) | (bf16rn(o1) << 16);
            pk.y = bf16rn(o2) | (bf16rn(o3) << 16);
            *(uint2*)(outb + (size_t)d * 128 + c4) = pk;
        }
    } else {
        // mean over 4 heads: lanes {hl, hl^8, hl^16, hl^24} share channel-in-head
        a0 += __shfl_xor(a0, 8); a0 += __shfl_xor(a0, 16);
        a1 += __shfl_xor(a1, 8); a1 += __shfl_xor(a1, 16);
        a2 += __shfl_xor(a2, 8); a2 += __shfl_xor(a2, 16);
        a3 += __shfl_xor(a3, 8); a3 += __shfl_xor(a3, 16);
        if (valid && hl < 8) {
            int cin = hl * 4;
            float4 o;
            o.x = elu1(a0 * 0.25f + bias[cin]);
            o.y = elu1(a1 * 0.25f + bias[cin + 1]);
            o.z = elu1(a2 * 0.25f + bias[cin + 2]);
            o.w = elu1(a3 * 0.25f + bias[cin + 3]);
            *(float4*)(outf + (size_t)d * 32 + cin) = o;
        }
    }
}

// ----------------- fused mean-pool + final_proj + MLP head, one block per batch row ---------
__global__ void poolmlp_kernel(const float* __restrict__ h2, const int* __restrict__ batch,
                               int n, const float* __restrict__ w_fp,
                               const float* __restrict__ b_fp, const float* __restrict__ w_m1,
                               const float* __restrict__ b_m1, const float* __restrict__ w_m2,
                               const float* __restrict__ b_m2, float* __restrict__ out) {
    int b = blockIdx.x, t = threadIdx.x; // 256 threads
    __shared__ int sb[2];
    if (t == 0) {
        int lo = 0, hi = n;
        while (lo < hi) { int mid = (lo + hi) >> 1; if (batch[mid] < b) lo = mid + 1; else hi = mid; }
        sb[0] = lo;
        int lo2 = lo, hi2 = n;
        while (lo2 < hi2) { int mid = (lo2 + hi2) >> 1; if (batch[mid] < b + 1) lo2 = mid + 1; else hi2 = mid; }
        sb[1] = lo2;
    }
    __syncthreads();
    int lo = sb[0], hi = sb[1];
    int c = t & 31, g = t >> 5; // 8 groups of 32
    float acc = 0.f;
    for (int i = lo + g; i < hi; i += 8) acc += h2[(size_t)i * 32 + c];
    __shared__ float red[8][32];
    __shared__ float sp[32], so[128];
    red[g][c] = acc;
    __syncthreads();
    if (t < 32) {
        float s = 0.f;
#pragma unroll
        for (int g2 = 0; g2 < 8; ++g2) s += red[g2][t];
        float cnt = (float)(hi - lo);
        sp[t] = s / fmaxf(cnt, 1.f);
    }
    __syncthreads();
    if (t < 128) {
        float o = b_fp[t];
#pragma unroll 8
        for (int k = 0; k < 32; ++k) o += sp[k] * w_fp[k * 128 + t];
        so[t] = o;
    }
    __syncthreads();
    if (t < 64) {
        float hm = b_m1[t];
        for (int cc = 0; cc < 128; ++cc) hm += so[cc] * w_m1[cc * 64 + t];
        float v = fmaxf(hm, 0.f) * w_m2[t];
#pragma unroll
        for (int offd = 32; offd > 0; offd >>= 1) v += __shfl_down(v, offd);
        if (t == 0) out[b] = v + b_m2[0];
    }
}

extern "C" void kernel_launch(void* const* d_in, const int* in_sizes, int n_in,
                              void* d_out, int out_size, void* d_ws, size_t ws_size,
                              hipStream_t stream) {
    const float* x = (const float*)d_in[0];
    const int* ei = (const int*)d_in[1];
    const int* batch = (const int*)d_in[2];
    const float* w_in = (const float*)d_in[3];
    const float* b_in = (const float*)d_in[4];
    const float* w[3] = {(const float*)d_in[5], (const float*)d_in[9], (const float*)d_in[13]};
    const float* asrc[3] = {(const float*)d_in[6], (const float*)d_in[10], (const float*)d_in[14]};
    const float* adst[3] = {(const float*)d_in[7], (const float*)d_in[11], (const float*)d_in[15]};
    const float* bb[3] = {(const float*)d_in[8], (const float*)d_in[12], (const float*)d_in[16]};
    const float* w_fp = (const float*)d_in[17];
    const float* b_fp = (const float*)d_in[18];
    const float* w_m1 = (const float*)d_in[19];
    const float* b_m1 = (const float*)d_in[20];
    const float* w_m2 = (const float*)d_in[21];
    const float* b_m2 = (const float*)d_in[22];

    int n = in_sizes[0] / 128;
    int e = in_sizes[1] / 2;
    int B = out_size;

    char* wsb = (char*)d_ws;
    size_t off = 0;
    auto alloc = [&](size_t bytes) -> void* {
        void* p = wsb + off;
        off += (bytes + 255) & ~(size_t)255;
        return p;
    };
    ushort* hAu = (ushort*)alloc((size_t)n * 128 * 2);  // proj out / agg concat out (bf16)
    ushort* hBu = (ushort*)alloc((size_t)n * 128 * 2);  // per-layer gemm out (bf16)
    float* h3 = (float*)alloc((size_t)n * 32 * 4);      // layer-3 agg out (fp32)
    float* als = (float*)alloc((size_t)n * 4 * 4);
    float* ald = (float*)alloc((size_t)n * 4 * 4);
    int* deg = (int*)alloc((size_t)n * 4);              // reused as cursor
    int* rowp = (int*)alloc((size_t)(n + 1) * 4);
    int* col = (int*)alloc((size_t)(e + 8) * 4);
    int* bsums = (int*)alloc(4096);
    ushort* whi = (ushort*)alloc((size_t)4 * 16384 * 2);
    ushort* wlo = (ushort*)alloc((size_t)4 * 16384 * 2);

    const int* srcp = ei;
    const int* dstp = ei + e;

    // XCD-partitioned dst-CSR — graph shared by all 3 layers
    hipMemsetAsync(deg, 0, (size_t)n * 4, stream);
    hist_kernel<<<1024, 256, 0, stream>>>(dstp, e, n, deg);
    int nb = (n + 2047) / 2048;
    scan1_kernel<<<nb, 256, 0, stream>>>(deg, n, rowp, bsums);
    scan3_kernel<<<nb, 256, 0, stream>>>(rowp, bsums, n, e, deg);
    fill_kernel<<<1024, 256, 0, stream>>>(srcp, dstp, e, n, deg, col);

    // pre-pack all 4 weight matrices into bf16 hi/lo MFMA fragment order
    wpack_kernel<<<256, 256, 0, stream>>>(w_in, w[0], w[1], w[2], whi, wlo);

    int ntiles = (n + 31) / 32;
    int gblk = ntiles < 512 ? ntiles : 512;

    // input projection (fp32 A split hi/lo, bias, bf16 out)
    gemm_mfma_kernel<true, false, false><<<gblk, 512, 0, stream>>>(
        x, whi, wlo, b_in, hAu, n, ntiles, nullptr, nullptr, nullptr, nullptr);

    // 3 GAT layers: mfma gemm hAu->hBu (bf16 A, +fused al), fused-exp aggregate
    int gridAgg = (n + 7) / 8; // 2 nodes/wave, 4 waves/block
    for (int L = 0; L < 3; ++L) {
        gemm_mfma_kernel<false, true, true><<<gblk, 512, 0, stream>>>(
            hAu, whi + (size_t)(L + 1) * 16384, wlo + (size_t)(L + 1) * 16384, nullptr, hBu, n,
            ntiles, asrc[L], adst[L], als, ald);
        if (L < 2)
            agg_kernel<true><<<gridAgg, 256, 0, stream>>>(hBu, als, ald, rowp, col, bb[L],
                                                          hAu, nullptr, n);
        else
            agg_kernel<false><<<gridAgg, 256, 0, stream>>>(hBu, als, ald, rowp, col, bb[L],
                                                           nullptr, h3, n);
    }

    // fused pooling + MLP head
    poolmlp_kernel<<<B, 256, 0, stream>>>(h3, batch, n, w_fp, b_fp, w_m1, b_m1, w_m2, b_m2,
                                          (float*)d_out);
}

// Round 11
// 287.774 us; speedup vs baseline: 1.4236x; 1.0293x over previous
//
#include <hip/hip_runtime.h>

#define NEG 0.2f

typedef short s16x8 __attribute__((ext_vector_type(8)));
typedef float f32x4 __attribute__((ext_vector_type(4)));

__device__ __forceinline__ float lrelu(float x) { return x >= 0.f ? x : NEG * x; }
__device__ __forceinline__ float elu1(float x) { return x > 0.f ? x : __expf(x) - 1.f; }

__device__ __forceinline__ unsigned bf16rn(float f) {
    unsigned u = __float_as_uint(f);
    u += 0x7fffu + ((u >> 16) & 1u);
    return u >> 16;
}
__device__ __forceinline__ float bf16tof(ushort h) {
    return __uint_as_float(((unsigned)h) << 16);
}
__device__ __forceinline__ float bf16lo(unsigned u) { return __uint_as_float(u << 16); }
__device__ __forceinline__ float bf16hi(unsigned u) { return __uint_as_float(u & 0xffff0000u); }

// ----------------- XCD-partitioned dst-CSR build -----------------
__global__ void hist_kernel(const int* __restrict__ dst, int e, int n, int* __restrict__ deg) {
    int p = blockIdx.x & 7;
    int s = blockIdx.x >> 3;
    int nslices = gridDim.x >> 3;
    int rng = (n + 7) >> 3;
    int lo = p * rng, hi = min(n, lo + rng);
    int chunk = (e + nslices - 1) / nslices;
    int i0 = s * chunk, i1 = min(e, i0 + chunk);
    for (int i = i0 + threadIdx.x; i < i1; i += blockDim.x) {
        int d = dst[i];
        if (d >= lo && d < hi) atomicAdd(&deg[d], 1);
    }
}

__device__ __forceinline__ int waveIncScanI(int v, int lane) {
#pragma unroll
    for (int off = 1; off < 64; off <<= 1) {
        int u = __shfl_up(v, off);
        if (lane >= off) v += u;
    }
    return v;
}

__global__ void scan1_kernel(const int* __restrict__ deg, int nk,
                             int* __restrict__ rowp, int* __restrict__ bsums) {
    int t = threadIdx.x;
    int base = blockIdx.x * 2048 + t * 8;
    int vals[8];
    int sum = 0;
#pragma unroll
    for (int i = 0; i < 8; ++i) {
        int idx = base + i;
        int v = (idx < nk) ? deg[idx] : 0;
        vals[i] = sum;
        sum += v;
    }
    int lane = t & 63, w = t >> 6;
    int inc = waveIncScanI(sum, lane);
    __shared__ int wsums[4];
    if (lane == 63) wsums[w] = inc;
    __syncthreads();
    int wpre = 0;
#pragma unroll
    for (int i = 0; i < 3; ++i) wpre += (i < w) ? wsums[i] : 0;
    int exc = wpre + inc - sum;
#pragma unroll
    for (int i = 0; i < 8; ++i) {
        int idx = base + i;
        if (idx < nk) rowp[idx] = exc + vals[i];
    }
    if (t == 255) bsums[blockIdx.x] = wpre + inc;
}

// scan3: per-block prefix computed locally from bsums (merged scan2), copy cursor
__global__ void scan3_kernel(int* __restrict__ rowp, const int* __restrict__ bsums,
                             int nk, int total, int* __restrict__ cursor) {
    int g = blockIdx.x;
    __shared__ int spre;
    if (threadIdx.x < 64) {
        int lane = threadIdx.x;
        int v = 0;
        for (int base = lane; base < g; base += 64) v += bsums[base];
#pragma unroll
        for (int off = 32; off > 0; off >>= 1) v += __shfl_xor(v, off);
        if (lane == 0) spre = v;
    }
    __syncthreads();
    int pre = spre;
    int base = g * 2048 + threadIdx.x * 8;
#pragma unroll
    for (int i = 0; i < 8; ++i) {
        int idx = base + i;
        if (idx < nk) {
            int v = rowp[idx] + pre;
            rowp[idx] = v;
            cursor[idx] = v;
        } else if (idx == nk) {
            rowp[nk] = total;
        }
    }
}

__global__ void fill_kernel(const int* __restrict__ src, const int* __restrict__ dst, int e,
                            int n, int* __restrict__ cursor, int* __restrict__ col) {
    int p = blockIdx.x & 7;
    int s = blockIdx.x >> 3;
    int nslices = gridDim.x >> 3;
    int rng = (n + 7) >> 3;
    int lo = p * rng, hi = min(n, lo + rng);
    int chunk = (e + nslices - 1) / nslices;
    int i0 = s * chunk, i1 = min(e, i0 + chunk);
    for (int i = i0 + threadIdx.x; i < i1; i += blockDim.x) {
        int d = dst[i];
        if (d >= lo && d < hi) {
            int pos = atomicAdd(&cursor[d], 1);
            col[pos] = src[i];
        }
    }
}

// ----------------- W pre-pack (3 layers): layer 0 = w_in@w0 (folded proj), layers 1,2 direct.
// Also emits b_eff = b_in @ w0. Output: bf16 hi/lo in MFMA B-frag order.
__global__ void wpack_kernel(const float* __restrict__ w_in, const float* __restrict__ w0,
                             const float* __restrict__ w1, const float* __restrict__ w2,
                             const float* __restrict__ b_in,
                             ushort* __restrict__ whi, ushort* __restrict__ wlo,
                             float* __restrict__ beff) {
    int idx = blockIdx.x * 256 + threadIdx.x; // 3*16384
    if (idx >= 3 * 16384) return;
    int layer = idx >> 14, e = idx & 16383;
    int k = e >> 7, c = e & 127;
    float wv;
    if (layer == 0) {
        float s = 0.f;
        for (int m = 0; m < 128; ++m) s += w_in[k * 128 + m] * w0[m * 128 + c];
        wv = s;
    } else {
        const float* W = (layer == 1) ? w1 : w2;
        wv = W[e];
    }
    ushort hi = (ushort)bf16rn(wv);
    ushort lo = (ushort)bf16rn(wv - bf16tof(hi));
    int kt = k >> 5, kk = k & 31, j = kk & 7;
    int ln = ((kk >> 3) << 4) | (c & 15);
    int ntg = c >> 4;
    int pos = (layer << 14) + (((kt << 3) + ntg) * 64 + ln) * 8 + j;
    whi[pos] = hi;
    wlo[pos] = lo;
    if (idx < 128) {
        float s = 0.f;
        for (int m = 0; m < 128; ++m) s += b_in[m] * w0[m * 128 + idx];
        beff[idx] = s;
    }
}

// ----------------- MFMA split-bf16 GEMM: out[n,128](bf16) = A[n,128] @ W[128,128] (+bias)
// ABF16: A rows are bf16 (exact) -> 4 MFMAs/kt; else fp32 A split hi/lo -> 6 MFMAs/kt.
// AL logits computed from biased output (bias=0 for layers 1,2).
template <bool BIAS, bool AL, bool ABF16>
__global__ __launch_bounds__(512, 4) void gemm_mfma_kernel(
    const void* __restrict__ Av, const ushort* __restrict__ whi, const ushort* __restrict__ wlo,
    const float* __restrict__ bias, ushort* __restrict__ outb, int n, int ntiles,
    const float* __restrict__ asrc, const float* __restrict__ adst,
    float* __restrict__ als, float* __restrict__ ald) {
    __shared__ s16x8 ahi[2][4][64];
    __shared__ s16x8 alo[2][4][64];
    int t = threadIdx.x;
    int wid = t >> 6, lane = t & 63;
    int ntp = wid & 3;    // head / 32-col pair
    int mhalf = wid >> 2; // which 16-row half

    const s16x8* wph = (const s16x8*)whi;
    const s16x8* wpl = (const s16x8*)wlo;
    s16x8 wh[4][2], wl[4][2];
#pragma unroll
    for (int kt = 0; kt < 4; ++kt)
#pragma unroll
        for (int j = 0; j < 2; ++j) {
            int ntg = ntp * 2 + j;
            wh[kt][j] = wph[((kt << 3) + ntg) * 64 + lane];
            wl[kt][j] = wpl[((kt << 3) + ntg) * 64 + lane];
        }

    int c0 = ntp * 32 + (lane & 15);
    int c1 = c0 + 16;
    float bv0 = 0.f, bv1 = 0.f;
    if (BIAS) { bv0 = bias[c0]; bv1 = bias[c1]; }
    float as0 = 0.f, as1 = 0.f, ad0 = 0.f, ad1 = 0.f;
    if (AL) {
        as0 = asrc[ntp * 32 + (lane & 15)];
        as1 = asrc[ntp * 32 + 16 + (lane & 15)];
        ad0 = adst[ntp * 32 + (lane & 15)];
        ad1 = adst[ntp * 32 + 16 + (lane & 15)];
    }

    int srow = t >> 4, skoct = t & 15;
    int smh = srow >> 4, skt = skoct >> 2;
    int sln = ((skoct & 3) << 4) | (srow & 15);

    for (int tile = blockIdx.x; tile < ntiles; tile += gridDim.x) {
        int r0 = tile * 32;
        {
            int gr = r0 + srow;
            if (ABF16) {
                const ushort* Ab = (const ushort*)Av;
                s16x8 hi = {0, 0, 0, 0, 0, 0, 0, 0};
                if (gr < n) hi = *(const s16x8*)(Ab + (size_t)gr * 128 + skoct * 8);
                ahi[smh][skt][sln] = hi;
            } else {
                const float* Af = (const float*)Av;
                float4 v0 = make_float4(0.f, 0.f, 0.f, 0.f), v1 = v0;
                if (gr < n) {
                    const float4* rp = (const float4*)(Af + (size_t)gr * 128 + skoct * 8);
                    v0 = rp[0];
                    v1 = rp[1];
                }
                float f[8] = {v0.x, v0.y, v0.z, v0.w, v1.x, v1.y, v1.z, v1.w};
                s16x8 hi, lo;
#pragma unroll
                for (int j = 0; j < 8; ++j) {
                    ushort h = (ushort)bf16rn(f[j]);
                    hi[j] = (short)h;
                    lo[j] = (short)bf16rn(f[j] - bf16tof(h));
                }
                ahi[smh][skt][sln] = hi;
                alo[smh][skt][sln] = lo;
            }
        }
        __syncthreads();

        f32x4 acc0 = {0.f, 0.f, 0.f, 0.f};
        f32x4 acc1 = {0.f, 0.f, 0.f, 0.f};
#pragma unroll
        for (int kt = 0; kt < 4; ++kt) {
            s16x8 ah = ahi[mhalf][kt][lane];
            if (ABF16) {
                acc0 = __builtin_amdgcn_mfma_f32_16x16x32_bf16(ah, wh[kt][0], acc0, 0, 0, 0);
                acc0 = __builtin_amdgcn_mfma_f32_16x16x32_bf16(ah, wl[kt][0], acc0, 0, 0, 0);
                acc1 = __builtin_amdgcn_mfma_f32_16x16x32_bf16(ah, wh[kt][1], acc1, 0, 0, 0);
                acc1 = __builtin_amdgcn_mfma_f32_16x16x32_bf16(ah, wl[kt][1], acc1, 0, 0, 0);
            } else {
                s16x8 al = alo[mhalf][kt][lane];
                acc0 = __builtin_amdgcn_mfma_f32_16x16x32_bf16(ah, wh[kt][0], acc0, 0, 0, 0);
                acc0 = __builtin_amdgcn_mfma_f32_16x16x32_bf16(ah, wl[kt][0], acc0, 0, 0, 0);
                acc0 = __builtin_amdgcn_mfma_f32_16x16x32_bf16(al, wh[kt][0], acc0, 0, 0, 0);
                acc1 = __builtin_amdgcn_mfma_f32_16x16x32_bf16(ah, wh[kt][1], acc1, 0, 0, 0);
                acc1 = __builtin_amdgcn_mfma_f32_16x16x32_bf16(ah, wl[kt][1], acc1, 0, 0, 0);
                acc1 = __builtin_amdgcn_mfma_f32_16x16x32_bf16(al, wh[kt][1], acc1, 0, 0, 0);
            }
        }

        int rbase = r0 + mhalf * 16 + (lane >> 4) * 4;
#pragma unroll
        for (int i = 0; i < 4; ++i) {
            int r = rbase + i;
            float o0 = acc0[i] + bv0;
            float o1 = acc1[i] + bv1;
            if (r < n) {
                outb[(size_t)r * 128 + c0] = (ushort)bf16rn(o0);
                outb[(size_t)r * 128 + c1] = (ushort)bf16rn(o1);
            }
            if (AL) {
                float ps = o0 * as0 + o1 * as1;
                float pd = o0 * ad0 + o1 * ad1;
                ps += __shfl_xor(ps, 1); ps += __shfl_xor(ps, 2);
                ps += __shfl_xor(ps, 4); ps += __shfl_xor(ps, 8);
                pd += __shfl_xor(pd, 1); pd += __shfl_xor(pd, 2);
                pd += __shfl_xor(pd, 4); pd += __shfl_xor(pd, 8);
                if ((lane & 15) == 0 && r < n) {
                    als[r * 4 + ntp] = ps;
                    ald[r * 4 + ntp] = pd;
                }
            }
        }
        __syncthreads();
    }
}

// ----------------- GAT aggregation: TWO nodes per wave (32 lanes / 4 channels each);
// exp(lrelu(..)) computed in-kernel by lane specialization (j=slot, hh=head) + shfl;
// bf16 rows; inline self-loop. se selected from the already-loaded ca/cb (no reload). ---------
template <bool CONCAT>
__global__ void agg_kernel(const ushort* __restrict__ hp, const float* __restrict__ als,
                           const float* __restrict__ ald_, const int* __restrict__ rowp,
                           const int* __restrict__ col, const float* __restrict__ bias,
                           ushort* __restrict__ outb, float* __restrict__ outf, int n) {
    int lane = threadIdx.x & 63;
    int hl = lane & 31;   // lane within half-wave
    int wid = (blockIdx.x * blockDim.x + threadIdx.x) >> 6;
    int d = wid * 2 + (lane >> 5);
    bool valid = d < n;
    int dc = valid ? d : (n - 1);

    int h = hl >> 3;      // data head (this lane's 4 channels)
    int c4 = hl * 4;      // channel base 0..124
    int hh = hl & 3;      // exp-duty head
    int jl = hl >> 2;     // exp-duty edge slot 0..7
    int bshf = lane & 32; // half base for shuffles

    int start = rowp[dc];
    int end = valid ? rowp[dc + 1] : start;

    float aldv_hh = ald_[dc * 4 + hh];
    float eself = __expf(lrelu(als[dc * 4 + h] + ald_[dc * 4 + h]));

    uint2 sv = *(const uint2*)(hp + (size_t)dc * 128 + c4);
    float a0 = eself * bf16lo(sv.x), a1 = eself * bf16hi(sv.x);
    float a2 = eself * bf16lo(sv.y), a3 = eself * bf16hi(sv.y);
    float esum = eself;

    int iters = (end - start + 7) >> 3;
    int oiters = __shfl_xor(iters, 32);
    int maxit = iters > oiters ? iters : oiters;
    unsigned nclamp = (unsigned)(n - 1);

    for (int it = 0; it < maxit; ++it) {
        int p0 = start + it * 8;
        bool act = p0 < end;
        int pc = act ? p0 : start;
        int4 ca = *(const int4*)(col + pc);
        int4 cb = *(const int4*)(col + pc + 4);
        // exp duty: this lane's (edge jl, head hh); select col[pc+jl] from ca/cb (uniform regs)
        int v0 = (jl & 4) ? cb.x : ca.x;
        int v1 = (jl & 4) ? cb.y : ca.y;
        int v2 = (jl & 4) ? cb.z : ca.z;
        int v3 = (jl & 4) ? cb.w : ca.w;
        int w0_ = (jl & 2) ? v2 : v0;
        int w1_ = (jl & 2) ? v3 : v1;
        unsigned se = (unsigned)((jl & 1) ? w1_ : w0_);
        se = se > nclamp ? nclamp : se;
        float ee = __expf(lrelu(als[(size_t)se * 4 + hh] + aldv_hh));
        ee = (act && (p0 + jl < end)) ? ee : 0.f;

#define EDGE(JJ, SRC)                                                              \
        {                                                                          \
            float ej = __shfl(ee, bshf | (JJ << 2) | h);                           \
            unsigned sju = (unsigned)(SRC);                                        \
            sju = sju > nclamp ? nclamp : sju;                                     \
            uint2 uv = *(const uint2*)(hp + (size_t)sju * 128 + c4);               \
            a0 += ej * bf16lo(uv.x); a1 += ej * bf16hi(uv.x);                      \
            a2 += ej * bf16lo(uv.y); a3 += ej * bf16hi(uv.y);                      \
            esum += ej;                                                            \
        }
        EDGE(0, ca.x) EDGE(1, ca.y) EDGE(2, ca.z) EDGE(3, ca.w)
        EDGE(4, cb.x) EDGE(5, cb.y) EDGE(6, cb.z) EDGE(7, cb.w)
#undef EDGE
    }

    float inv = 1.f / (esum + 1e-16f);
    a0 *= inv; a1 *= inv; a2 *= inv; a3 *= inv;
    if (CONCAT) {
        if (valid) {
            float o0 = elu1(a0 + bias[c4]);
            float o1 = elu1(a1 + bias[c4 + 1]);
            float o2 = elu1(a2 + bias[c4 + 2]);
            float o3 = elu1(a3 + bias[c4 + 3]);
            uint2 pk;
            pk.x = bf16rn(o0) | (bf16rn(o1) << 16);
            pk.y = bf16rn(o2) | (bf16rn(o3) << 16);
            *(uint2*)(outb + (size_t)d * 128 + c4) = pk;
        }
    } else {
        // mean over 4 heads: lanes {hl, hl^8, hl^16, hl^24} share channel-in-head
        a0 += __shfl_xor(a0, 8); a0 += __shfl_xor(a0, 16);
        a1 += __shfl_xor(a1, 8); a1 += __shfl_xor(a1, 16);
        a2 += __shfl_xor(a2, 8); a2 += __shfl_xor(a2, 16);
        a3 += __shfl_xor(a3, 8); a3 += __shfl_xor(a3, 16);
        if (valid && hl < 8) {
            int cin = hl * 4;
            float4 o;
            o.x = elu1(a0 * 0.25f + bias[cin]);
            o.y = elu1(a1 * 0.25f + bias[cin + 1]);
            o.z = elu1(a2 * 0.25f + bias[cin + 2]);
            o.w = elu1(a3 * 0.25f + bias[cin + 3]);
            *(float4*)(outf + (size_t)d * 32 + cin) = o;
        }
    }
}

// ----------------- fused mean-pool + final_proj + MLP head, one block per batch row ---------
__global__ void poolmlp_kernel(const float* __restrict__ h2, const int* __restrict__ batch,
                               int n, const float* __restrict__ w_fp,
                               const float* __restrict__ b_fp, const float* __restrict__ w_m1,
                               const float* __restrict__ b_m1, const float* __restrict__ w_m2,
                               const float* __restrict__ b_m2, float* __restrict__ out) {
    int b = blockIdx.x, t = threadIdx.x; // 256 threads
    __shared__ int sb[2];
    if (t == 0) {
        int lo = 0, hi = n;
        while (lo < hi) { int mid = (lo + hi) >> 1; if (batch[mid] < b) lo = mid + 1; else hi = mid; }
        sb[0] = lo;
        int lo2 = lo, hi2 = n;
        while (lo2 < hi2) { int mid = (lo2 + hi2) >> 1; if (batch[mid] < b + 1) lo2 = mid + 1; else hi2 = mid; }
        sb[1] = lo2;
    }
    __syncthreads();
    int lo = sb[0], hi = sb[1];
    int c = t & 31, g = t >> 5; // 8 groups of 32
    float acc = 0.f;
    for (int i = lo + g; i < hi; i += 8) acc += h2[(size_t)i * 32 + c];
    __shared__ float red[8][32];
    __shared__ float sp[32], so[128];
    red[g][c] = acc;
    __syncthreads();
    if (t < 32) {
        float s = 0.f;
#pragma unroll
        for (int g2 = 0; g2 < 8; ++g2) s += red[g2][t];
        float cnt = (float)(hi - lo);
        sp[t] = s / fmaxf(cnt, 1.f);
    }
    __syncthreads();
    if (t < 128) {
        float o = b_fp[t];
#pragma unroll 8
        for (int k = 0; k < 32; ++k) o += sp[k] * w_fp[k * 128 + t];
        so[t] = o;
    }
    __syncthreads();
    if (t < 64) {
        float hm = b_m1[t];
        for (int cc = 0; cc < 128; ++cc) hm += so[cc] * w_m1[cc * 64 + t];
        float v = fmaxf(hm, 0.f) * w_m2[t];
#pragma unroll
        for (int offd = 32; offd > 0; offd >>= 1) v += __shfl_down(v, offd);
        if (t == 0) out[b] = v + b_m2[0];
    }
}

extern "C" void kernel_launch(void* const* d_in, const int* in_sizes, int n_in,
                              void* d_out, int out_size, void* d_ws, size_t ws_size,
                              hipStream_t stream) {
    const float* x = (const float*)d_in[0];
    const int* ei = (const int*)d_in[1];
    const int* batch = (const int*)d_in[2];
    const float* w_in = (const float*)d_in[3];
    const float* b_in = (const float*)d_in[4];
    const float* w[3] = {(const float*)d_in[5], (const float*)d_in[9], (const float*)d_in[13]};
    const float* asrc[3] = {(const float*)d_in[6], (const float*)d_in[10], (const float*)d_in[14]};
    const float* adst[3] = {(const float*)d_in[7], (const float*)d_in[11], (const float*)d_in[15]};
    const float* bb[3] = {(const float*)d_in[8], (const float*)d_in[12], (const float*)d_in[16]};
    const float* w_fp = (const float*)d_in[17];
    const float* b_fp = (const float*)d_in[18];
    const float* w_m1 = (const float*)d_in[19];
    const float* b_m1 = (const float*)d_in[20];
    const float* w_m2 = (const float*)d_in[21];
    const float* b_m2 = (const float*)d_in[22];

    int n = in_sizes[0] / 128;
    int e = in_sizes[1] / 2;
    int B = out_size;

    char* wsb = (char*)d_ws;
    size_t off = 0;
    auto alloc = [&](size_t bytes) -> void* {
        void* p = wsb + off;
        off += (bytes + 255) & ~(size_t)255;
        return p;
    };
    ushort* hAu = (ushort*)alloc((size_t)n * 128 * 2);  // agg concat out (bf16)
    ushort* hBu = (ushort*)alloc((size_t)n * 128 * 2);  // per-layer gemm out (bf16)
    float* h3 = (float*)alloc((size_t)n * 32 * 4);      // layer-3 agg out (fp32)
    float* als = (float*)alloc((size_t)n * 4 * 4);
    float* ald = (float*)alloc((size_t)n * 4 * 4);
    int* deg = (int*)alloc((size_t)n * 4);              // reused as cursor
    int* rowp = (int*)alloc((size_t)(n + 1) * 4);
    int* col = (int*)alloc((size_t)(e + 8) * 4);
    int* bsums = (int*)alloc(4096);
    ushort* whi = (ushort*)alloc((size_t)3 * 16384 * 2);
    ushort* wlo = (ushort*)alloc((size_t)3 * 16384 * 2);
    float* beff = (float*)alloc(128 * 4);

    const int* srcp = ei;
    const int* dstp = ei + e;

    // XCD-partitioned dst-CSR — graph shared by all 3 layers
    hipMemsetAsync(deg, 0, (size_t)n * 4, stream);
    hist_kernel<<<1024, 256, 0, stream>>>(dstp, e, n, deg);
    int nb = (n + 2047) / 2048;
    scan1_kernel<<<nb, 256, 0, stream>>>(deg, n, rowp, bsums);
    scan3_kernel<<<nb, 256, 0, stream>>>(rowp, bsums, n, e, deg);
    fill_kernel<<<1024, 256, 0, stream>>>(srcp, dstp, e, n, deg, col);

    // pack weights: layer0 = w_in@w0 (folded projection), layers 1,2 direct; b_eff = b_in@w0
    wpack_kernel<<<192, 256, 0, stream>>>(w_in, w[0], w[1], w[2], b_in, whi, wlo, beff);

    int ntiles = (n + 31) / 32;
    int gblk = ntiles < 512 ? ntiles : 512;
    int gridAgg = (n + 7) / 8; // 2 nodes/wave, 4 waves/block

    // layer 0: folded gemm x @ w_eff + b_eff (fp32 A split hi/lo), fused AL
    gemm_mfma_kernel<true, true, false><<<gblk, 512, 0, stream>>>(
        x, whi, wlo, beff, hBu, n, ntiles, asrc[0], adst[0], als, ald);
    agg_kernel<true><<<gridAgg, 256, 0, stream>>>(hBu, als, ald, rowp, col, bb[0],
                                                  hAu, nullptr, n);

    // layers 1,2: gemm hAu->hBu (bf16 A, +fused AL), fused-exp aggregate
    for (int L = 1; L < 3; ++L) {
        gemm_mfma_kernel<false, true, true><<<gblk, 512, 0, stream>>>(
            hAu, whi + (size_t)L * 16384, wlo + (size_t)L * 16384, nullptr, hBu, n,
            ntiles, asrc[L], adst[L], als, ald);
        if (L < 2)
            agg_kernel<true><<<gridAgg, 256, 0, stream>>>(hBu, als, ald, rowp, col, bb[L],
                                                          hAu, nullptr, n);
        else
            agg_kernel<false><<<gridAgg, 256, 0, stream>>>(hBu, als, ald, rowp, col, bb[L],
                                                           nullptr, h3, n);
    }

    // fused pooling + MLP head
    poolmlp_kernel<<<B, 256, 0, stream>>>(h3, batch, n, w_fp, b_fp, w_m1, b_m1, w_m2, b_m2,
                                          (float*)d_out);
}

// Round 13
// 282.817 us; speedup vs baseline: 1.4486x; 1.0175x over previous
//
#include <hip/hip_runtime.h>

#define NEG 0.2f

typedef short s16x8 __attribute__((ext_vector_type(8)));
typedef float f32x4 __attribute__((ext_vector_type(4)));

__device__ __forceinline__ float lrelu(float x) { return x >= 0.f ? x : NEG * x; }
__device__ __forceinline__ float elu1(float x) { return x > 0.f ? x : __expf(x) - 1.f; }

__device__ __forceinline__ unsigned bf16rn(float f) {
    unsigned u = __float_as_uint(f);
    u += 0x7fffu + ((u >> 16) & 1u);
    return u >> 16;
}
__device__ __forceinline__ float bf16tof(ushort h) {
    return __uint_as_float(((unsigned)h) << 16);
}
__device__ __forceinline__ float bf16lo(unsigned u) { return __uint_as_float(u << 16); }
__device__ __forceinline__ float bf16hi(unsigned u) { return __uint_as_float(u & 0xffff0000u); }

// ----------------- XCD-partitioned dst-CSR build -----------------
__global__ void hist_kernel(const int* __restrict__ dst, int e, int n, int* __restrict__ deg) {
    int p = blockIdx.x & 7;
    int s = blockIdx.x >> 3;
    int nslices = gridDim.x >> 3;
    int rng = (n + 7) >> 3;
    int lo = p * rng, hi = min(n, lo + rng);
    int chunk = (e + nslices - 1) / nslices;
    int i0 = s * chunk, i1 = min(e, i0 + chunk);
    for (int i = i0 + threadIdx.x; i < i1; i += blockDim.x) {
        int d = dst[i];
        if (d >= lo && d < hi) atomicAdd(&deg[d], 1);
    }
}

__device__ __forceinline__ int waveIncScanI(int v, int lane) {
#pragma unroll
    for (int off = 1; off < 64; off <<= 1) {
        int u = __shfl_up(v, off);
        if (lane >= off) v += u;
    }
    return v;
}

__global__ void scan1_kernel(const int* __restrict__ deg, int nk,
                             int* __restrict__ rowp, int* __restrict__ bsums) {
    int t = threadIdx.x;
    int base = blockIdx.x * 2048 + t * 8;
    int vals[8];
    int sum = 0;
#pragma unroll
    for (int i = 0; i < 8; ++i) {
        int idx = base + i;
        int v = (idx < nk) ? deg[idx] : 0;
        vals[i] = sum;
        sum += v;
    }
    int lane = t & 63, w = t >> 6;
    int inc = waveIncScanI(sum, lane);
    __shared__ int wsums[4];
    if (lane == 63) wsums[w] = inc;
    __syncthreads();
    int wpre = 0;
#pragma unroll
    for (int i = 0; i < 3; ++i) wpre += (i < w) ? wsums[i] : 0;
    int exc = wpre + inc - sum;
#pragma unroll
    for (int i = 0; i < 8; ++i) {
        int idx = base + i;
        if (idx < nk) rowp[idx] = exc + vals[i];
    }
    if (t == 255) bsums[blockIdx.x] = wpre + inc;
}

// scan3: per-block prefix computed locally from bsums (merged scan2), copy cursor
__global__ void scan3_kernel(int* __restrict__ rowp, const int* __restrict__ bsums,
                             int nk, int total, int* __restrict__ cursor) {
    int g = blockIdx.x;
    __shared__ int spre;
    if (threadIdx.x < 64) {
        int lane = threadIdx.x;
        int v = 0;
        for (int base = lane; base < g; base += 64) v += bsums[base];
#pragma unroll
        for (int off = 32; off > 0; off >>= 1) v += __shfl_xor(v, off);
        if (lane == 0) spre = v;
    }
    __syncthreads();
    int pre = spre;
    int base = g * 2048 + threadIdx.x * 8;
#pragma unroll
    for (int i = 0; i < 8; ++i) {
        int idx = base + i;
        if (idx < nk) {
            int v = rowp[idx] + pre;
            rowp[idx] = v;
            cursor[idx] = v;
        } else if (idx == nk) {
            rowp[nk] = total;
        }
    }
}

__global__ void fill_kernel(const int* __restrict__ src, const int* __restrict__ dst, int e,
                            int n, int* __restrict__ cursor, int* __restrict__ col) {
    int p = blockIdx.x & 7;
    int s = blockIdx.x >> 3;
    int nslices = gridDim.x >> 3;
    int rng = (n + 7) >> 3;
    int lo = p * rng, hi = min(n, lo + rng);
    int chunk = (e + nslices - 1) / nslices;
    int i0 = s * chunk, i1 = min(e, i0 + chunk);
    for (int i = i0 + threadIdx.x; i < i1; i += blockDim.x) {
        int d = dst[i];
        if (d >= lo && d < hi) {
            int pos = atomicAdd(&cursor[d], 1);
            col[pos] = src[i];
        }
    }
}

// ----------------- W pre-pack (3 layers): layer 0 = w_in@w0 (folded proj), layers 1,2 direct.
// Also emits b_eff = b_in@w0, and zeroes deg (replaces memset dispatch).
__global__ void wpack_kernel(const float* __restrict__ w_in, const float* __restrict__ w0,
                             const float* __restrict__ w1, const float* __restrict__ w2,
                             const float* __restrict__ b_in,
                             ushort* __restrict__ whi, ushort* __restrict__ wlo,
                             float* __restrict__ beff, int n, int* __restrict__ degz) {
    int idx = blockIdx.x * 256 + threadIdx.x; // 3*16384 work items
    int stride = gridDim.x * 256;
    for (int i = idx; i < n; i += stride) degz[i] = 0;
    if (idx >= 3 * 16384) return;
    int layer = idx >> 14, e = idx & 16383;
    int k = e >> 7, c = e & 127;
    float wv;
    if (layer == 0) {
        float s = 0.f;
        for (int m = 0; m < 128; ++m) s += w_in[k * 128 + m] * w0[m * 128 + c];
        wv = s;
    } else {
        const float* W = (layer == 1) ? w1 : w2;
        wv = W[e];
    }
    ushort hi = (ushort)bf16rn(wv);
    ushort lo = (ushort)bf16rn(wv - bf16tof(hi));
    int kt = k >> 5, kk = k & 31, j = kk & 7;
    int ln = ((kk >> 3) << 4) | (c & 15);
    int ntg = c >> 4;
    int pos = (layer << 14) + (((kt << 3) + ntg) * 64 + ln) * 8 + j;
    whi[pos] = hi;
    wlo[pos] = lo;
    if (idx < 128) {
        float s = 0.f;
        for (int m = 0; m < 128; ++m) s += b_in[m] * w0[m * 128 + idx];
        beff[idx] = s;
    }
}

// ----------------- MFMA split-bf16 GEMM, double-buffered LDS staging (1 barrier/tile)
// out[n,128](bf16) = A[n,128] @ W[128,128] (+bias); fused attention logits from biased out.
template <bool BIAS, bool AL, bool ABF16>
__global__ __launch_bounds__(512, 2) void gemm_mfma_kernel(
    const void* __restrict__ Av, const ushort* __restrict__ whi, const ushort* __restrict__ wlo,
    const float* __restrict__ bias, ushort* __restrict__ outb, int n, int ntiles,
    const float* __restrict__ asrc, const float* __restrict__ adst,
    float* __restrict__ als, float* __restrict__ ald) {
    __shared__ s16x8 ahi[2][2][4][64]; // [dbuf][mhalf][kt][lane]
    __shared__ s16x8 alo[2][2][4][64];
    int t = threadIdx.x;
    int wid = t >> 6, lane = t & 63;
    int ntp = wid & 3;    // head / 32-col pair
    int mhalf = wid >> 2; // which 16-row half

    const s16x8* wph = (const s16x8*)whi;
    const s16x8* wpl = (const s16x8*)wlo;
    s16x8 wh[4][2], wl[4][2];
#pragma unroll
    for (int kt = 0; kt < 4; ++kt)
#pragma unroll
        for (int j = 0; j < 2; ++j) {
            int ntg = ntp * 2 + j;
            wh[kt][j] = wph[((kt << 3) + ntg) * 64 + lane];
            wl[kt][j] = wpl[((kt << 3) + ntg) * 64 + lane];
        }

    int c0 = ntp * 32 + (lane & 15);
    int c1 = c0 + 16;
    float bv0 = 0.f, bv1 = 0.f;
    if (BIAS) { bv0 = bias[c0]; bv1 = bias[c1]; }
    float as0 = 0.f, as1 = 0.f, ad0 = 0.f, ad1 = 0.f;
    if (AL) {
        as0 = asrc[ntp * 32 + (lane & 15)];
        as1 = asrc[ntp * 32 + 16 + (lane & 15)];
        ad0 = adst[ntp * 32 + (lane & 15)];
        ad1 = adst[ntp * 32 + 16 + (lane & 15)];
    }

    int srow = t >> 4, skoct = t & 15;
    int smh = srow >> 4, skt = skoct >> 2;
    int sln = ((skoct & 3) << 4) | (srow & 15);

    auto stage = [&](int tile, int bi) {
        int gr = tile * 32 + srow;
        if (ABF16) {
            const ushort* Ab = (const ushort*)Av;
            s16x8 hi = {0, 0, 0, 0, 0, 0, 0, 0};
            if (gr < n) hi = *(const s16x8*)(Ab + (size_t)gr * 128 + skoct * 8);
            ahi[bi][smh][skt][sln] = hi;
        } else {
            const float* Af = (const float*)Av;
            float4 v0 = make_float4(0.f, 0.f, 0.f, 0.f), v1 = v0;
            if (gr < n) {
                const float4* rp = (const float4*)(Af + (size_t)gr * 128 + skoct * 8);
                v0 = rp[0];
                v1 = rp[1];
            }
            float f[8] = {v0.x, v0.y, v0.z, v0.w, v1.x, v1.y, v1.z, v1.w};
            s16x8 hi, lo;
#pragma unroll
            for (int j = 0; j < 8; ++j) {
                ushort h = (ushort)bf16rn(f[j]);
                hi[j] = (short)h;
                lo[j] = (short)bf16rn(f[j] - bf16tof(h));
            }
            ahi[bi][smh][skt][sln] = hi;
            alo[bi][smh][skt][sln] = lo;
        }
    };

    int tile = blockIdx.x;
    if (tile < ntiles) stage(tile, 0);
    int cur = 0;
    __syncthreads();

    for (; tile < ntiles; tile += gridDim.x) {
        int nxt = tile + gridDim.x;
        if (nxt < ntiles) stage(nxt, cur ^ 1);

        f32x4 acc0 = {0.f, 0.f, 0.f, 0.f};
        f32x4 acc1 = {0.f, 0.f, 0.f, 0.f};
#pragma unroll
        for (int kt = 0; kt < 4; ++kt) {
            s16x8 ah = ahi[cur][mhalf][kt][lane];
            if (ABF16) {
                acc0 = __builtin_amdgcn_mfma_f32_16x16x32_bf16(ah, wh[kt][0], acc0, 0, 0, 0);
                acc0 = __builtin_amdgcn_mfma_f32_16x16x32_bf16(ah, wl[kt][0], acc0, 0, 0, 0);
                acc1 = __builtin_amdgcn_mfma_f32_16x16x32_bf16(ah, wh[kt][1], acc1, 0, 0, 0);
                acc1 = __builtin_amdgcn_mfma_f32_16x16x32_bf16(ah, wl[kt][1], acc1, 0, 0, 0);
            } else {
                s16x8 al = alo[cur][mhalf][kt][lane];
                acc0 = __builtin_amdgcn_mfma_f32_16x16x32_bf16(ah, wh[kt][0], acc0, 0, 0, 0);
                acc0 = __builtin_amdgcn_mfma_f32_16x16x32_bf16(ah, wl[kt][0], acc0, 0, 0, 0);
                acc0 = __builtin_amdgcn_mfma_f32_16x16x32_bf16(al, wh[kt][0], acc0, 0, 0, 0);
                acc1 = __builtin_amdgcn_mfma_f32_16x16x32_bf16(ah, wh[kt][1], acc1, 0, 0, 0);
                acc1 = __builtin_amdgcn_mfma_f32_16x16x32_bf16(ah, wl[kt][1], acc1, 0, 0, 0);
                acc1 = __builtin_amdgcn_mfma_f32_16x16x32_bf16(al, wh[kt][1], acc1, 0, 0, 0);
            }
        }

        int rbase = tile * 32 + mhalf * 16 + (lane >> 4) * 4;
#pragma unroll
        for (int i = 0; i < 4; ++i) {
            int r = rbase + i;
            float o0 = acc0[i] + bv0;
            float o1 = acc1[i] + bv1;
            if (r < n) {
                outb[(size_t)r * 128 + c0] = (ushort)bf16rn(o0);
                outb[(size_t)r * 128 + c1] = (ushort)bf16rn(o1);
            }
            if (AL) {
                float ps = o0 * as0 + o1 * as1;
                float pd = o0 * ad0 + o1 * ad1;
                ps += __shfl_xor(ps, 1); ps += __shfl_xor(ps, 2);
                ps += __shfl_xor(ps, 4); ps += __shfl_xor(ps, 8);
                pd += __shfl_xor(pd, 1); pd += __shfl_xor(pd, 2);
                pd += __shfl_xor(pd, 4); pd += __shfl_xor(pd, 8);
                if ((lane & 15) == 0 && r < n) {
                    als[r * 4 + ntp] = ps;
                    ald[r * 4 + ntp] = pd;
                }
            }
        }
        __syncthreads();
        cur ^= 1;
    }
}

// ----------------- GAT aggregation: TWO nodes per wave (32 lanes / 4 channels each);
// exp(lrelu(..)) by lane specialization + shfl; bf16 rows; inline self-loop. -----------------
template <bool CONCAT>
__global__ void agg_kernel(const ushort* __restrict__ hp, const float* __restrict__ als,
                           const float* __restrict__ ald_, const int* __restrict__ rowp,
                           const int* __restrict__ col, const float* __restrict__ bias,
                           ushort* __restrict__ outb, float* __restrict__ outf, int n) {
    int lane = threadIdx.x & 63;
    int hl = lane & 31;   // lane within half-wave
    int wid = (blockIdx.x * blockDim.x + threadIdx.x) >> 6;
    int d = wid * 2 + (lane >> 5);
    bool valid = d < n;
    int dc = valid ? d : (n - 1);

    int h = hl >> 3;      // data head (this lane's 4 channels)
    int c4 = hl * 4;      // channel base 0..124
    int hh = hl & 3;      // exp-duty head
    int jl = hl >> 2;     // exp-duty edge slot 0..7
    int bshf = lane & 32; // half base for shuffles

    int start = rowp[dc];
    int end = valid ? rowp[dc + 1] : start;

    float aldv_hh = ald_[dc * 4 + hh];
    float eself = __expf(lrelu(als[dc * 4 + h] + ald_[dc * 4 + h]));

    uint2 sv = *(const uint2*)(hp + (size_t)dc * 128 + c4);
    float a0 = eself * bf16lo(sv.x), a1 = eself * bf16hi(sv.x);
    float a2 = eself * bf16lo(sv.y), a3 = eself * bf16hi(sv.y);
    float esum = eself;

    int iters = (end - start + 7) >> 3;
    int oiters = __shfl_xor(iters, 32);
    int maxit = iters > oiters ? iters : oiters;
    unsigned nclamp = (unsigned)(n - 1);

    for (int it = 0; it < maxit; ++it) {
        int p0 = start + it * 8;
        bool act = p0 < end;
        int pc = act ? p0 : start;
        int4 ca = *(const int4*)(col + pc);
        int4 cb = *(const int4*)(col + pc + 4);
        int v0 = (jl & 4) ? cb.x : ca.x;
        int v1 = (jl & 4) ? cb.y : ca.y;
        int v2 = (jl & 4) ? cb.z : ca.z;
        int v3 = (jl & 4) ? cb.w : ca.w;
        int w0_ = (jl & 2) ? v2 : v0;
        int w1_ = (jl & 2) ? v3 : v1;
        unsigned se = (unsigned)((jl & 1) ? w1_ : w0_);
        se = se > nclamp ? nclamp : se;
        float ee = __expf(lrelu(als[(size_t)se * 4 + hh] + aldv_hh));
        ee = (act && (p0 + jl < end)) ? ee : 0.f;

#define EDGE(JJ, SRC)                                                              \
        {                                                                          \
            float ej = __shfl(ee, bshf | (JJ << 2) | h);                           \
            unsigned sju = (unsigned)(SRC);                                        \
            sju = sju > nclamp ? nclamp : sju;                                     \
            uint2 uv = *(const uint2*)(hp + (size_t)sju * 128 + c4);               \
            a0 += ej * bf16lo(uv.x); a1 += ej * bf16hi(uv.x);                      \
            a2 += ej * bf16lo(uv.y); a3 += ej * bf16hi(uv.y);                      \
            esum += ej;                                                            \
        }
        EDGE(0, ca.x) EDGE(1, ca.y) EDGE(2, ca.z) EDGE(3, ca.w)
        EDGE(4, cb.x) EDGE(5, cb.y) EDGE(6, cb.z) EDGE(7, cb.w)
#undef EDGE
    }

    float inv = 1.f / (esum + 1e-16f);
    a0 *= inv; a1 *= inv; a2 *= inv; a3 *= inv;
    if (CONCAT) {
        if (valid) {
            float o0 = elu1(a0 + bias[c4]);
            float o1 = elu1(a1 + bias[c4 + 1]);
            float o2 = elu1(a2 + bias[c4 + 2]);
            float o3 = elu1(a3 + bias[c4 + 3]);
            uint2 pk;
            pk.x = bf16rn(o0) | (bf16rn(o1) << 16);
            pk.y = bf16rn(o2) | (bf16rn(o3) << 16);
            *(uint2*)(outb + (size_t)d * 128 + c4) = pk;
        }
    } else {
        a0 += __shfl_xor(a0, 8); a0 += __shfl_xor(a0, 16);
        a1 += __shfl_xor(a1, 8); a1 += __shfl_xor(a1, 16);
        a2 += __shfl_xor(a2, 8); a2 += __shfl_xor(a2, 16);
        a3 += __shfl_xor(a3, 8); a3 += __shfl_xor(a3, 16);
        if (valid && hl < 8) {
            int cin = hl * 4;
            float4 o;
            o.x = elu1(a0 * 0.25f + bias[cin]);
            o.y = elu1(a1 * 0.25f + bias[cin + 1]);
            o.z = elu1(a2 * 0.25f + bias[cin + 2]);
            o.w = elu1(a3 * 0.25f + bias[cin + 3]);
            *(float4*)(outf + (size_t)d * 32 + cin) = o;
        }
    }
}

// ----------------- fused mean-pool + final_proj + MLP head, one block per batch row ---------
__global__ void poolmlp_kernel(const float* __restrict__ h2, const int* __restrict__ batch,
                               int n, const float* __restrict__ w_fp,
                               const float* __restrict__ b_fp, const float* __restrict__ w_m1,
                               const float* __restrict__ b_m1, const float* __restrict__ w_m2,
                               const float* __restrict__ b_m2, float* __restrict__ out) {
    int b = blockIdx.x, t = threadIdx.x; // 256 threads
    __shared__ int sb[2];
    if (t == 0) {
        int lo = 0, hi = n;
        while (lo < hi) { int mid = (lo + hi) >> 1; if (batch[mid] < b) lo = mid + 1; else hi = mid; }
        sb[0] = lo;
        int lo2 = lo, hi2 = n;
        while (lo2 < hi2) { int mid = (lo2 + hi2) >> 1; if (batch[mid] < b + 1) lo2 = mid + 1; else hi2 = mid; }
        sb[1] = lo2;
    }
    __syncthreads();
    int lo = sb[0], hi = sb[1];
    int c = t & 31, g = t >> 5; // 8 groups of 32
    float acc = 0.f;
    for (int i = lo + g; i < hi; i += 8) acc += h2[(size_t)i * 32 + c];
    __shared__ float red[8][32];
    __shared__ float sp[32], so[128];
    red[g][c] = acc;
    __syncthreads();
    if (t < 32) {
        float s = 0.f;
#pragma unroll
        for (int g2 = 0; g2 < 8; ++g2) s += red[g2][t];
        float cnt = (float)(hi - lo);
        sp[t] = s / fmaxf(cnt, 1.f);
    }
    __syncthreads();
    if (t < 128) {
        float o = b_fp[t];
#pragma unroll 8
        for (int k = 0; k < 32; ++k) o += sp[k] * w_fp[k * 128 + t];
        so[t] = o;
    }
    __syncthreads();
    if (t < 64) {
        float hm = b_m1[t];
        for (int cc = 0; cc < 128; ++cc) hm += so[cc] * w_m1[cc * 64 + t];
        float v = fmaxf(hm, 0.f) * w_m2[t];
#pragma unroll
        for (int offd = 32; offd > 0; offd >>= 1) v += __shfl_down(v, offd);
        if (t == 0) out[b] = v + b_m2[0];
    }
}

extern "C" void kernel_launch(void* const* d_in, const int* in_sizes, int n_in,
                              void* d_out, int out_size, void* d_ws, size_t ws_size,
                              hipStream_t stream) {
    const float* x = (const float*)d_in[0];
    const int* ei = (const int*)d_in[1];
    const int* batch = (const int*)d_in[2];
    const float* w_in = (const float*)d_in[3];
    const float* b_in = (const float*)d_in[4];
    const float* w[3] = {(const float*)d_in[5], (const float*)d_in[9], (const float*)d_in[13]};
    const float* asrc[3] = {(const float*)d_in[6], (const float*)d_in[10], (const float*)d_in[14]};
    const float* adst[3] = {(const float*)d_in[7], (const float*)d_in[11], (const float*)d_in[15]};
    const float* bb[3] = {(const float*)d_in[8], (const float*)d_in[12], (const float*)d_in[16]};
    const float* w_fp = (const float*)d_in[17];
    const float* b_fp = (const float*)d_in[18];
    const float* w_m1 = (const float*)d_in[19];
    const float* b_m1 = (const float*)d_in[20];
    const float* w_m2 = (const float*)d_in[21];
    const float* b_m2 = (const float*)d_in[22];

    int n = in_sizes[0] / 128;
    int e = in_sizes[1] / 2;
    int B = out_size;

    char* wsb = (char*)d_ws;
    size_t off = 0;
    auto alloc = [&](size_t bytes) -> void* {
        void* p = wsb + off;
        off += (bytes + 255) & ~(size_t)255;
        return p;
    };
    ushort* hAu = (ushort*)alloc((size_t)n * 128 * 2);  // agg concat out (bf16)
    ushort* hBu = (ushort*)alloc((size_t)n * 128 * 2);  // per-layer gemm out (bf16)
    float* h3 = (float*)alloc((size_t)n * 32 * 4);      // layer-3 agg out (fp32)
    float* als = (float*)alloc((size_t)n * 4 * 4);
    float* ald = (float*)alloc((size_t)n * 4 * 4);
    int* deg = (int*)alloc((size_t)n * 4);              // reused as cursor
    int* rowp = (int*)alloc((size_t)(n + 1) * 4);
    int* col = (int*)alloc((size_t)(e + 8) * 4);
    int* bsums = (int*)alloc(4096);
    ushort* whi = (ushort*)alloc((size_t)3 * 16384 * 2);
    ushort* wlo = (ushort*)alloc((size_t)3 * 16384 * 2);
    float* beff = (float*)alloc(128 * 4);

    const int* srcp = ei;
    const int* dstp = ei + e;

    // weights pack + zero deg (1 dispatch, replaces memset)
    wpack_kernel<<<192, 256, 0, stream>>>(w_in, w[0], w[1], w[2], b_in, whi, wlo, beff,
                                          n, deg);

    // XCD-partitioned dst-CSR — graph shared by all 3 layers
    hist_kernel<<<1024, 256, 0, stream>>>(dstp, e, n, deg);
    int nb = (n + 2047) / 2048;
    scan1_kernel<<<nb, 256, 0, stream>>>(deg, n, rowp, bsums);
    scan3_kernel<<<nb, 256, 0, stream>>>(rowp, bsums, n, e, deg);
    fill_kernel<<<1024, 256, 0, stream>>>(srcp, dstp, e, n, deg, col);

    int ntiles = (n + 31) / 32;
    int gblk = ntiles < 512 ? ntiles : 512;
    int gridAgg = (n + 7) / 8; // 2 nodes/wave, 4 waves/block

    // layer 0: folded gemm x @ (w_in@w0) + b_in@w0 (fp32 A split hi/lo), fused AL
    gemm_mfma_kernel<true, true, false><<<gblk, 512, 0, stream>>>(
        x, whi, wlo, beff, hBu, n, ntiles, asrc[0], adst[0], als, ald);
    agg_kernel<true><<<gridAgg, 256, 0, stream>>>(hBu, als, ald, rowp, col, bb[0],
                                                  hAu, nullptr, n);

    // layers 1,2: gemm hAu->hBu (bf16 A, +fused AL), fused-exp aggregate
    for (int L = 1; L < 3; ++L) {
        gemm_mfma_kernel<false, true, true><<<gblk, 512, 0, stream>>>(
            hAu, whi + (size_t)L * 16384, wlo + (size_t)L * 16384, nullptr, hBu, n,
            ntiles, asrc[L], adst[L], als, ald);
        if (L < 2)
            agg_kernel<true><<<gridAgg, 256, 0, stream>>>(hBu, als, ald, rowp, col, bb[L],
                                                          hAu, nullptr, n);
        else
            agg_kernel<false><<<gridAgg, 256, 0, stream>>>(hBu, als, ald, rowp, col, bb[L],
                                                           nullptr, h3, n);
    }

    // fused pooling + MLP head
    poolmlp_kernel<<<B, 256, 0, stream>>>(h3, batch, n, w_fp, b_fp, w_m1, b_m1, w_m2, b_m2,
                                          (float*)d_out);
}